// Round 1
// baseline (831.559 us; speedup 1.0000x reference)
//
#include <hip/hip_runtime.h>
#include <hip/hip_bf16.h>

#define BB 2
#define NN 2048
#define II 768
#define CC 256
#define DD 64

typedef __attribute__((ext_vector_type(8))) short short8;
typedef __attribute__((ext_vector_type(4))) float f32x4;

static constexpr float SCALE = 0.036084391824351615f; // 1/sqrt(768)

__device__ __forceinline__ unsigned short f2bf(float f) {
  union { float f; unsigned int u; } v; v.f = f;
  unsigned int u = v.u;
  unsigned int r = u + 0x7fffu + ((u >> 16) & 1u);
  return (unsigned short)(r >> 16);
}
__device__ __forceinline__ float bf2f(unsigned short h) {
  union { unsigned int u; float f; } v; v.u = ((unsigned int)h) << 16;
  return v.f;
}

union U8 { unsigned short us[8]; uint4 v; };

// ---------------------------------------------------------------------------
// Projection GEMM: out[m][j] = sum_i A[m][i] * W[j][i]   (A [M,768] f32,
// W [768,768] f32, out bf16).  64x64 tile, 4 waves, bf16 MFMA 16x16x32.
// LDS tiles XOR-swizzled in 8-element groups to kill ds_read_b128 conflicts.
// ---------------------------------------------------------------------------
__global__ __launch_bounds__(256, 2)
void proj_kernel(const float* __restrict__ A, const float* __restrict__ W,
                 unsigned short* __restrict__ out)
{
  const int m0 = blockIdx.x * 64;
  const int j0 = blockIdx.y * 64;
  const int tid = threadIdx.x;
  const int lane = tid & 63, wv = tid >> 6;
  const int lrow = lane & 15, khi = lane >> 4;

  __shared__ __align__(16) unsigned short a_lds[64 * 128];
  __shared__ __align__(16) unsigned short w_lds[64 * 128];

  f32x4 acc[4] = {};

  for (int ic = 0; ic < 6; ++ic) {
    __syncthreads();
    #pragma unroll
    for (int u = 0; u < 4; ++u) {
      int idx = u * 256 + tid;          // 1024 groups of 8
      int row = idx >> 4, gp = idx & 15;
      int g = gp ^ (row & 7);           // source group for this (swizzled) slot
      const float* srcA = A + (size_t)(m0 + row) * II + ic * 128 + g * 8;
      const float* srcW = W + (size_t)(j0 + row) * II + ic * 128 + g * 8;
      float4 a0 = *(const float4*)srcA; float4 a1 = *(const float4*)(srcA + 4);
      float4 w0 = *(const float4*)srcW; float4 w1 = *(const float4*)(srcW + 4);
      U8 ua, uw;
      ua.us[0] = f2bf(a0.x); ua.us[1] = f2bf(a0.y); ua.us[2] = f2bf(a0.z); ua.us[3] = f2bf(a0.w);
      ua.us[4] = f2bf(a1.x); ua.us[5] = f2bf(a1.y); ua.us[6] = f2bf(a1.z); ua.us[7] = f2bf(a1.w);
      uw.us[0] = f2bf(w0.x); uw.us[1] = f2bf(w0.y); uw.us[2] = f2bf(w0.z); uw.us[3] = f2bf(w0.w);
      uw.us[4] = f2bf(w1.x); uw.us[5] = f2bf(w1.y); uw.us[6] = f2bf(w1.z); uw.us[7] = f2bf(w1.w);
      *(uint4*)&a_lds[idx * 8] = ua.v;
      *(uint4*)&w_lds[idx * 8] = uw.v;
    }
    __syncthreads();
    #pragma unroll
    for (int s = 0; s < 4; ++s) {       // 4 k-steps of 32 within the 128-chunk
      int g = s * 4 + khi;              // 8-elem group along i
      int ar = 16 * wv + lrow;
      short8 af = *(const short8*)&a_lds[(ar * 16 + (g ^ (ar & 7))) * 8];
      #pragma unroll
      for (int f = 0; f < 4; ++f) {
        int br = f * 16 + lrow;
        short8 bfr = *(const short8*)&w_lds[(br * 16 + (g ^ (br & 7))) * 8];
        acc[f] = __builtin_amdgcn_mfma_f32_16x16x32_bf16(af, bfr, acc[f], 0, 0, 0);
      }
    }
  }
  #pragma unroll
  for (int f = 0; f < 4; ++f) {
    #pragma unroll
    for (int r = 0; r < 4; ++r) {
      int row = m0 + 16 * wv + khi * 4 + r;   // D layout: row=(lane>>4)*4+reg
      int col = j0 + f * 16 + lrow;           //           col=lane&15
      out[(size_t)row * II + col] = f2bf(acc[f][r]);
    }
  }
}

// ---------------------------------------------------------------------------
// Attention score passes.  Block = one (b,c): 64 desc rows x 2048 note tokens.
// 4 waves, each owns a 16-row strip; Q fragments live in registers (24 x
// bf16x8 per lane).  K streamed through 32KB swizzled LDS in 256-wide i-chunks.
// PASS1: online softmax stats (m,l) per d-row.  PASS2: recompute S and reduce
// over valid d into pp[b,c,n] = sum_d dmask*exp(S-m)/l/denom.
// ---------------------------------------------------------------------------
template <int PASS>
__global__ __launch_bounds__(256, 2)
void attn_pass(const unsigned short* __restrict__ Qp,
               const unsigned short* __restrict__ Kp,
               const int* __restrict__ amask, const int* __restrict__ dmask,
               float* __restrict__ m_ws, float* __restrict__ l_ws,
               float* __restrict__ pp_ws)
{
  const int c = blockIdx.x, b = blockIdx.y;
  const int tid = threadIdx.x;
  const int lane = tid & 63, wv = tid >> 6;
  const int lrow = lane & 15, khi = lane >> 4;

  __shared__ __align__(16) unsigned short k_lds[64 * 256]; // 32 KB
  __shared__ float red_lds[4 * 64];

  short8 aq[24];
  {
    const unsigned short* qr = Qp + (size_t)(c * 64 + 16 * wv + lrow) * II + khi * 8;
    #pragma unroll
    for (int s = 0; s < 24; ++s) aq[s] = *(const short8*)(qr + s * 32);
  }

  float m_run[4], l_run[4], wgt[4];
  if (PASS == 1) {
    #pragma unroll
    for (int r = 0; r < 4; ++r) { m_run[r] = -3.0e38f; l_run[r] = 0.0f; }
    #pragma unroll
    for (int r = 0; r < 4; ++r) wgt[r] = 0.0f;
  } else {
    float dm = (dmask[c * 64 + lane] != 0) ? 1.0f : 0.0f;
    #pragma unroll
    for (int m = 1; m < 64; m <<= 1) dm += __shfl_xor(dm, m);
    const float inv_dm = 1.0f / dm;
    #pragma unroll
    for (int r = 0; r < 4; ++r) {
      int d = 16 * wv + khi * 4 + r;
      int gi = (b * CC + c) * 64 + d;
      m_run[r] = m_ws[gi];
      float l = l_ws[gi];
      wgt[r] = (dmask[c * 64 + d] != 0) ? (inv_dm / l) : 0.0f;
    }
  }

  for (int nt = 0; nt < 32; ++nt) {
    const int n0 = nt * 64;
    f32x4 acc[4] = {};
    #pragma unroll
    for (int ic = 0; ic < 3; ++ic) {
      __syncthreads();
      #pragma unroll
      for (int u = 0; u < 8; ++u) {
        int idx = u * 256 + tid;        // 2048 groups of 8 bf16
        int row = idx >> 5, gp = idx & 31;
        int g = gp ^ (row & 7);
        const unsigned short* src =
            Kp + (size_t)(b * NN + n0 + row) * II + ic * 256 + g * 8;
        *(uint4*)&k_lds[idx * 8] = *(const uint4*)src;
      }
      __syncthreads();
      #pragma unroll
      for (int s = 0; s < 8; ++s) {
        int g = s * 4 + khi;
        short8 af = aq[ic * 8 + s];
        #pragma unroll
        for (int f = 0; f < 4; ++f) {
          int br = f * 16 + lrow;
          short8 bfr = *(const short8*)&k_lds[(br * 32 + (g ^ (br & 7))) * 8];
          acc[f] = __builtin_amdgcn_mfma_f32_16x16x32_bf16(af, bfr, acc[f], 0, 0, 0);
        }
      }
    }
    // scale + note-token mask (reference: where(mask, s*scale, -1e9))
    float sv[4][4];
    #pragma unroll
    for (int f = 0; f < 4; ++f) {
      bool valid = amask[b * NN + n0 + f * 16 + lrow] != 0;
      #pragma unroll
      for (int r = 0; r < 4; ++r)
        sv[f][r] = valid ? acc[f][r] * SCALE : -1.0e9f;
    }
    if (PASS == 1) {
      #pragma unroll
      for (int r = 0; r < 4; ++r) {
        float tmax = fmaxf(fmaxf(sv[0][r], sv[1][r]), fmaxf(sv[2][r], sv[3][r]));
        tmax = fmaxf(tmax, __shfl_xor(tmax, 1));
        tmax = fmaxf(tmax, __shfl_xor(tmax, 2));
        tmax = fmaxf(tmax, __shfl_xor(tmax, 4));
        tmax = fmaxf(tmax, __shfl_xor(tmax, 8));
        float mn = fmaxf(m_run[r], tmax);
        float sum = __expf(sv[0][r] - mn) + __expf(sv[1][r] - mn)
                  + __expf(sv[2][r] - mn) + __expf(sv[3][r] - mn);
        sum += __shfl_xor(sum, 1); sum += __shfl_xor(sum, 2);
        sum += __shfl_xor(sum, 4); sum += __shfl_xor(sum, 8);
        l_run[r] = l_run[r] * __expf(m_run[r] - mn) + sum;
        m_run[r] = mn;
      }
    } else {
      #pragma unroll
      for (int f = 0; f < 4; ++f) {
        float p = wgt[0] * __expf(sv[f][0] - m_run[0])
                + wgt[1] * __expf(sv[f][1] - m_run[1])
                + wgt[2] * __expf(sv[f][2] - m_run[2])
                + wgt[3] * __expf(sv[f][3] - m_run[3]);
        p += __shfl_xor(p, 16);
        p += __shfl_xor(p, 32);
        if (khi == 0) red_lds[wv * 64 + f * 16 + lrow] = p;
      }
      __syncthreads();
      if (tid < 64) {
        float t = red_lds[tid] + red_lds[64 + tid] + red_lds[128 + tid] + red_lds[192 + tid];
        pp_ws[(size_t)(b * CC + c) * NN + n0 + tid] = t;
      }
      // next-tile barriers (ic=0 staging) order red_lds reuse
    }
  }
  if (PASS == 1 && lrow == 0) {
    #pragma unroll
    for (int r = 0; r < 4; ++r) {
      int d = 16 * wv + khi * 4 + r;
      int gi = (b * CC + c) * 64 + d;
      m_ws[gi] = m_run[r];
      l_ws[gi] = l_run[r];
    }
  }
}

// ---------------------------------------------------------------------------
// pooled[b,c,i] = sum_n pp[b,c,n] * V[b,n,i]   (tiny 1.6 GF, vector f32)
// block: 8 consecutive c for one b; thread owns 3 i-columns.
// ---------------------------------------------------------------------------
__global__ __launch_bounds__(256)
void pv_kernel(const float* __restrict__ pp, const unsigned short* __restrict__ Vp,
               float* __restrict__ pooled)
{
  const int b = blockIdx.y, c0 = blockIdx.x * 8;
  const int tid = threadIdx.x;
  __shared__ float pp_lds[8 * 64];
  float acc[8][3] = {};
  for (int n0 = 0; n0 < NN; n0 += 64) {
    __syncthreads();
    #pragma unroll
    for (int u = 0; u < 2; ++u) {
      int idx = u * 256 + tid;
      int cc = idx >> 6, nn = idx & 63;
      pp_lds[idx] = pp[(size_t)(b * CC + c0 + cc) * NN + n0 + nn];
    }
    __syncthreads();
    for (int nn = 0; nn < 64; ++nn) {
      const unsigned short* vr = Vp + (size_t)(b * NN + n0 + nn) * II;
      float v0 = bf2f(vr[tid]);
      float v1 = bf2f(vr[tid + 256]);
      float v2 = bf2f(vr[tid + 512]);
      #pragma unroll
      for (int cc = 0; cc < 8; ++cc) {
        float p = pp_lds[cc * 64 + nn];
        acc[cc][0] += p * v0; acc[cc][1] += p * v1; acc[cc][2] += p * v2;
      }
    }
  }
  #pragma unroll
  for (int cc = 0; cc < 8; ++cc) {
    float* dst = pooled + (size_t)(b * CC + c0 + cc) * II;
    dst[tid] = acc[cc][0];
    dst[tid + 256] = acc[cc][1];
    dst[tid + 512] = acc[cc][2];
  }
}

// ---------------------------------------------------------------------------
// LayerNorm over i + dot with Wo.  One block per (b,c).
// ---------------------------------------------------------------------------
__global__ __launch_bounds__(256)
void ln_out_kernel(const float* __restrict__ pooled, const float* __restrict__ g,
                   const float* __restrict__ beta, const float* __restrict__ Wo,
                   const float* __restrict__ bo, float* __restrict__ out)
{
  const int bc = blockIdx.x;
  const int tid = threadIdx.x;
  const int lane = tid & 63, wv = tid >> 6;
  const float* row = pooled + (size_t)bc * II;
  float x0 = row[tid], x1 = row[tid + 256], x2 = row[tid + 512];
  float s = x0 + x1 + x2;
  float sq = x0 * x0 + x1 * x1 + x2 * x2;
  #pragma unroll
  for (int m = 1; m < 64; m <<= 1) { s += __shfl_xor(s, m); sq += __shfl_xor(sq, m); }
  __shared__ float red[8];
  if (lane == 0) { red[wv] = s; red[4 + wv] = sq; }
  __syncthreads();
  s = red[0] + red[1] + red[2] + red[3];
  sq = red[4] + red[5] + red[6] + red[7];
  const float mu = s * (1.0f / 768.0f);
  const float var = sq * (1.0f / 768.0f) - mu * mu;
  const float rs = rsqrtf(var + 1e-5f);
  float dot = ((x0 - mu) * rs * g[tid] + beta[tid]) * Wo[tid]
            + ((x1 - mu) * rs * g[tid + 256] + beta[tid + 256]) * Wo[tid + 256]
            + ((x2 - mu) * rs * g[tid + 512] + beta[tid + 512]) * Wo[tid + 512];
  #pragma unroll
  for (int m = 1; m < 64; m <<= 1) dot += __shfl_xor(dot, m);
  __syncthreads();
  if (lane == 0) red[wv] = dot;
  __syncthreads();
  if (tid == 0) out[bc] = red[0] + red[1] + red[2] + red[3] + bo[0];
}

// ---------------------------------------------------------------------------
extern "C" void kernel_launch(void* const* d_in, const int* in_sizes, int n_in,
                              void* d_out, int out_size, void* d_ws, size_t ws_size,
                              hipStream_t stream) {
  const float* x     = (const float*)d_in[0];   // [B,N,I]
  const int*   amask = (const int*)d_in[1];     // [B,N]
  const float* demb  = (const float*)d_in[2];   // [C,D,I]
  const int*   dmask = (const int*)d_in[3];     // [C,D]
  const float* Wq    = (const float*)d_in[4];
  const float* Wk    = (const float*)d_in[5];
  const float* Wv    = (const float*)d_in[6];
  const float* Wo    = (const float*)d_in[7];   // [1,I]
  const float* bo    = (const float*)d_in[8];   // [1]
  const float* lng   = (const float*)d_in[9];
  const float* lnb   = (const float*)d_in[10];

  char* ws = (char*)d_ws;
  const size_t OFF_Q  = 0;
  const size_t OFF_K  = OFF_Q + (size_t)CC * DD * II * 2;
  const size_t OFF_V  = OFF_K + (size_t)BB * NN * II * 2;
  const size_t OFF_M  = OFF_V + (size_t)BB * NN * II * 2;
  const size_t OFF_L  = OFF_M + (size_t)BB * CC * DD * 4;
  const size_t OFF_PP = OFF_L + (size_t)BB * CC * DD * 4;
  const size_t OFF_PL = OFF_PP + (size_t)BB * CC * NN * 4;

  unsigned short* Qp = (unsigned short*)(ws + OFF_Q);
  unsigned short* Kp = (unsigned short*)(ws + OFF_K);
  unsigned short* Vp = (unsigned short*)(ws + OFF_V);
  float* m_ws   = (float*)(ws + OFF_M);
  float* l_ws   = (float*)(ws + OFF_L);
  float* pp     = (float*)(ws + OFF_PP);
  float* pooled = (float*)(ws + OFF_PL);

  proj_kernel<<<dim3((CC * DD) / 64, II / 64), 256, 0, stream>>>(demb, Wq, Qp);
  proj_kernel<<<dim3((BB * NN) / 64, II / 64), 256, 0, stream>>>(x, Wk, Kp);
  proj_kernel<<<dim3((BB * NN) / 64, II / 64), 256, 0, stream>>>(x, Wv, Vp);
  attn_pass<1><<<dim3(CC, BB), 256, 0, stream>>>(Qp, Kp, amask, dmask, m_ws, l_ws, nullptr);
  attn_pass<2><<<dim3(CC, BB), 256, 0, stream>>>(Qp, Kp, amask, dmask, m_ws, l_ws, pp);
  pv_kernel<<<dim3(CC / 8, BB), 256, 0, stream>>>(pp, Vp, pooled);
  ln_out_kernel<<<BB * CC, 256, 0, stream>>>(pooled, lng, lnb, Wo, bo, (float*)d_out);
}

// Round 2
// 350.313 us; speedup vs baseline: 2.3738x; 2.3738x over previous
//
#include <hip/hip_runtime.h>
#include <hip/hip_bf16.h>

#define BB 2
#define NN 2048
#define II 768
#define CC 256
#define DD 64
#define MM (CC * DD)   // 16384 q-rows

typedef __attribute__((ext_vector_type(8))) short short8;
typedef __attribute__((ext_vector_type(4))) float f32x4;

static constexpr float SCALE = 0.036084391824351615f; // 1/sqrt(768)

__device__ __forceinline__ unsigned short f2bf(float f) {
  union { float f; unsigned int u; } v; v.f = f;
  unsigned int u = v.u;
  unsigned int r = u + 0x7fffu + ((u >> 16) & 1u);
  return (unsigned short)(r >> 16);
}

union U8 { unsigned short us[8]; uint4 v; };

#define GLOAD_LDS16(gp, lp)                                                    \
  __builtin_amdgcn_global_load_lds(                                            \
      (const __attribute__((address_space(1))) unsigned int*)(gp),             \
      (__attribute__((address_space(3))) unsigned int*)(lp), 16, 0, 0)

// ---------------------------------------------------------------------------
// Projection GEMM: out[m][j] = sum_i A[m][i] * W[j][i]  (A,W f32; out bf16).
// 64x64 tile, 4 waves.  MODE 0: out row-major [m][j].
// MODE 1 (V): out transposed Vt[(b*II + j)*NN + n] where m = b*NN + n.
// ---------------------------------------------------------------------------
template <int MODE>
__global__ __launch_bounds__(256, 2)
void proj_kernel(const float* __restrict__ A, const float* __restrict__ W,
                 unsigned short* __restrict__ out)
{
  const int m0 = blockIdx.x * 64;
  const int j0 = blockIdx.y * 64;
  const int tid = threadIdx.x;
  const int lane = tid & 63, wv = tid >> 6;
  const int lrow = lane & 15, khi = lane >> 4;

  __shared__ __align__(16) unsigned short a_lds[64 * 128];
  __shared__ __align__(16) unsigned short w_lds[64 * 128];

  f32x4 acc[4] = {};

  for (int ic = 0; ic < 6; ++ic) {
    __syncthreads();
    #pragma unroll
    for (int u = 0; u < 4; ++u) {
      int idx = u * 256 + tid;          // 1024 groups of 8
      int row = idx >> 4, gp = idx & 15;
      int g = gp ^ (row & 7);           // source group for this (swizzled) slot
      const float* srcA = A + (size_t)(m0 + row) * II + ic * 128 + g * 8;
      const float* srcW = W + (size_t)(j0 + row) * II + ic * 128 + g * 8;
      float4 a0 = *(const float4*)srcA; float4 a1 = *(const float4*)(srcA + 4);
      float4 w0 = *(const float4*)srcW; float4 w1 = *(const float4*)(srcW + 4);
      U8 ua, uw;
      ua.us[0] = f2bf(a0.x); ua.us[1] = f2bf(a0.y); ua.us[2] = f2bf(a0.z); ua.us[3] = f2bf(a0.w);
      ua.us[4] = f2bf(a1.x); ua.us[5] = f2bf(a1.y); ua.us[6] = f2bf(a1.z); ua.us[7] = f2bf(a1.w);
      uw.us[0] = f2bf(w0.x); uw.us[1] = f2bf(w0.y); uw.us[2] = f2bf(w0.z); uw.us[3] = f2bf(w0.w);
      uw.us[4] = f2bf(w1.x); uw.us[5] = f2bf(w1.y); uw.us[6] = f2bf(w1.z); uw.us[7] = f2bf(w1.w);
      *(uint4*)&a_lds[idx * 8] = ua.v;
      *(uint4*)&w_lds[idx * 8] = uw.v;
    }
    __syncthreads();
    #pragma unroll
    for (int s = 0; s < 4; ++s) {       // 4 k-steps of 32 within the 128-chunk
      int g = s * 4 + khi;
      int ar = 16 * wv + lrow;
      short8 af = *(const short8*)&a_lds[(ar * 16 + (g ^ (ar & 7))) * 8];
      #pragma unroll
      for (int f = 0; f < 4; ++f) {
        int br = f * 16 + lrow;
        short8 bfr = *(const short8*)&w_lds[(br * 16 + (g ^ (br & 7))) * 8];
        acc[f] = __builtin_amdgcn_mfma_f32_16x16x32_bf16(af, bfr, acc[f], 0, 0, 0);
      }
    }
  }
  #pragma unroll
  for (int f = 0; f < 4; ++f) {
    #pragma unroll
    for (int r = 0; r < 4; ++r) {
      int row = m0 + 16 * wv + khi * 4 + r;
      int col = j0 + f * 16 + lrow;
      if (MODE == 0) {
        out[(size_t)row * II + col] = f2bf(acc[f][r]);
      } else {
        int bb = row >> 11, n = row & (NN - 1);
        out[((size_t)bb * II + col) * NN + n] = f2bf(acc[f][r]);
      }
    }
  }
}

// ---------------------------------------------------------------------------
// Attention score GEMM (m97-style): S[b][m][n] = sum_i Q[m][i]*K[b][n][i],
// 128x128 tile, BK=64, 4 waves (2x2), global_load_lds w16, XOR-swizzled src.
// PASS1 epilogue: per-row partial sum of amask*exp(S*scale) -> l_part[b][nt][m].
// PASS2 epilogue: pp[b][c][n] = (1/denom_c) * sum_d dmask*exp(S*scale)/l_d.
// ---------------------------------------------------------------------------
template <int PASS>
__global__ __launch_bounds__(256, 2)
void attn_gemm(const unsigned short* __restrict__ Qp,
               const unsigned short* __restrict__ Kp,
               const int* __restrict__ amask,
               const int* __restrict__ dmask,
               const float* __restrict__ l_in,
               float* __restrict__ lpart_out,
               unsigned short* __restrict__ pp_out)
{
  const int m0 = blockIdx.x * 128;
  const int n0 = blockIdx.y * 128;
  const int b  = blockIdx.z;
  const int tid = threadIdx.x;
  const int lane = tid & 63, wv = tid >> 6;
  const int lrow = lane & 15, khi = lane >> 4;
  const int wr = wv >> 1, wc = wv & 1;

  __shared__ __align__(16) unsigned short a_lds[128 * 64];
  __shared__ __align__(16) unsigned short b_lds[128 * 64];
  __shared__ float red_lds[128 * 2];

  const unsigned short* Kb = Kp + (size_t)b * NN * II;

  f32x4 acc[4][4] = {};

  for (int kc = 0; kc < 12; ++kc) {
    const int k0 = kc * 64;
    __syncthreads();
    #pragma unroll
    for (int u = 0; u < 4; ++u) {
      int idx = u * 256 + tid;          // 1024 slots of 8 bf16 (16B)
      int row = idx >> 3, g = idx & 7;
      int sg = g ^ (row & 7);
      GLOAD_LDS16(Qp + (size_t)(m0 + row) * II + k0 + sg * 8, &a_lds[idx * 8]);
      GLOAD_LDS16(Kb + (size_t)(n0 + row) * II + k0 + sg * 8, &b_lds[idx * 8]);
    }
    __syncthreads();
    #pragma unroll
    for (int s = 0; s < 2; ++s) {
      short8 af[4], bf[4];
      #pragma unroll
      for (int m = 0; m < 4; ++m) {
        int ar = wr * 64 + m * 16 + lrow;
        int g = s * 4 + khi;
        af[m] = *(const short8*)&a_lds[(ar * 8 + (g ^ (ar & 7))) * 8];
      }
      #pragma unroll
      for (int f = 0; f < 4; ++f) {
        int br = wc * 64 + f * 16 + lrow;
        int g = s * 4 + khi;
        bf[f] = *(const short8*)&b_lds[(br * 8 + (g ^ (br & 7))) * 8];
      }
      #pragma unroll
      for (int m = 0; m < 4; ++m)
        #pragma unroll
        for (int f = 0; f < 4; ++f)
          acc[m][f] = __builtin_amdgcn_mfma_f32_16x16x32_bf16(af[m], bf[f], acc[m][f], 0, 0, 0);
    }
  }

  float msk[4];
  #pragma unroll
  for (int f = 0; f < 4; ++f)
    msk[f] = (amask[b * NN + n0 + wc * 64 + f * 16 + lrow] != 0) ? 1.0f : 0.0f;

  if (PASS == 1) {
    #pragma unroll
    for (int m = 0; m < 4; ++m) {
      #pragma unroll
      for (int r = 0; r < 4; ++r) {
        float p = msk[0] * __expf(acc[m][0][r] * SCALE)
                + msk[1] * __expf(acc[m][1][r] * SCALE)
                + msk[2] * __expf(acc[m][2][r] * SCALE)
                + msk[3] * __expf(acc[m][3][r] * SCALE);
        p += __shfl_xor(p, 1); p += __shfl_xor(p, 2);
        p += __shfl_xor(p, 4); p += __shfl_xor(p, 8);
        if (lrow == 0)
          red_lds[(wr * 64 + m * 16 + khi * 4 + r) * 2 + wc] = p;
      }
    }
    __syncthreads();
    if (tid < 128)
      lpart_out[((size_t)(b * 16 + blockIdx.y) << 14) + m0 + tid] =
          red_lds[tid * 2] + red_lds[tid * 2 + 1];
  } else {
    // per-lane row weights: dmask/l for my 16 rows (all in one c per wave)
    float wrow[4][4];
    float dsum = 0.0f;
    #pragma unroll
    for (int m = 0; m < 4; ++m) {
      #pragma unroll
      for (int r = 0; r < 4; ++r) {
        int row = m0 + wr * 64 + m * 16 + khi * 4 + r;
        float dm = (dmask[row] != 0) ? 1.0f : 0.0f;
        dsum += dm;
        wrow[m][r] = dm / l_in[((size_t)b << 14) + row];
      }
    }
    dsum += __shfl_xor(dsum, 1);  dsum += __shfl_xor(dsum, 2);
    dsum += __shfl_xor(dsum, 4);  dsum += __shfl_xor(dsum, 8);
    dsum += __shfl_xor(dsum, 16); dsum += __shfl_xor(dsum, 32);
    const float inv_denom = 16.0f / dsum;  // denom_c = dsum/16
    const int c = blockIdx.x * 2 + wr;
    #pragma unroll
    for (int f = 0; f < 4; ++f) {
      float p = 0.0f;
      #pragma unroll
      for (int m = 0; m < 4; ++m)
        #pragma unroll
        for (int r = 0; r < 4; ++r)
          p += wrow[m][r] * __expf(acc[m][f][r] * SCALE);
      p *= msk[f] * inv_denom;
      p += __shfl_xor(p, 16);
      p += __shfl_xor(p, 32);
      if (khi == 0)
        pp_out[((size_t)(b * CC + c)) * NN + n0 + wc * 64 + f * 16 + lrow] = f2bf(p);
    }
  }
}

// ---------------------------------------------------------------------------
// l reduce: l[b][m] = sum_nt l_part[b][nt][m]
// ---------------------------------------------------------------------------
__global__ __launch_bounds__(256)
void lred_kernel(const float* __restrict__ lp, float* __restrict__ l)
{
  int i = blockIdx.x * 256 + threadIdx.x;      // 0 .. 32767
  int b = i >> 14, m = i & (MM - 1);
  float s = 0.0f;
  #pragma unroll
  for (int nt = 0; nt < 16; ++nt)
    s += lp[((size_t)(b * 16 + nt) << 14) + m];
  l[i] = s;
}

// ---------------------------------------------------------------------------
// PV GEMM: pooled[mc][j] = sum_n pp[mc][n] * Vt[b*II + j][n]   (f32 out)
// 64x64 tile, 4 waves, K-chunks of 128 over n=2048.
// ---------------------------------------------------------------------------
__global__ __launch_bounds__(256, 2)
void pv_gemm(const unsigned short* __restrict__ pp,
             const unsigned short* __restrict__ Vt,
             float* __restrict__ pooled)
{
  const int m0 = blockIdx.x * 64;
  const int j0 = blockIdx.y * 64;
  const int b  = m0 >> 8;
  const int tid = threadIdx.x;
  const int lane = tid & 63, wv = tid >> 6;
  const int lrow = lane & 15, khi = lane >> 4;

  __shared__ __align__(16) unsigned short a_lds[64 * 128];
  __shared__ __align__(16) unsigned short b_lds[64 * 128];

  f32x4 acc[4] = {};

  for (int kc = 0; kc < 16; ++kc) {
    const int k0 = kc * 128;
    __syncthreads();
    #pragma unroll
    for (int u = 0; u < 4; ++u) {
      int idx = u * 256 + tid;          // 1024 slots of 8 bf16
      int row = idx >> 4, g = idx & 15;
      int sg = g ^ (row & 7);
      GLOAD_LDS16(pp + (size_t)(m0 + row) * NN + k0 + sg * 8, &a_lds[idx * 8]);
      GLOAD_LDS16(Vt + ((size_t)b * II + j0 + row) * NN + k0 + sg * 8, &b_lds[idx * 8]);
    }
    __syncthreads();
    #pragma unroll
    for (int s = 0; s < 4; ++s) {
      int g = s * 4 + khi;
      int ar = 16 * wv + lrow;
      short8 af = *(const short8*)&a_lds[(ar * 16 + (g ^ (ar & 7))) * 8];
      #pragma unroll
      for (int f = 0; f < 4; ++f) {
        int br = f * 16 + lrow;
        short8 bfr = *(const short8*)&b_lds[(br * 16 + (g ^ (br & 7))) * 8];
        acc[f] = __builtin_amdgcn_mfma_f32_16x16x32_bf16(af, bfr, acc[f], 0, 0, 0);
      }
    }
  }
  #pragma unroll
  for (int f = 0; f < 4; ++f)
    #pragma unroll
    for (int r = 0; r < 4; ++r) {
      int row = m0 + 16 * wv + khi * 4 + r;
      int col = j0 + f * 16 + lrow;
      pooled[(size_t)row * II + col] = acc[f][r];
    }
}

// ---------------------------------------------------------------------------
// LayerNorm over i + dot with Wo.  One block per (b,c).
// ---------------------------------------------------------------------------
__global__ __launch_bounds__(256)
void ln_out_kernel(const float* __restrict__ pooled, const float* __restrict__ g,
                   const float* __restrict__ beta, const float* __restrict__ Wo,
                   const float* __restrict__ bo, float* __restrict__ out)
{
  const int bc = blockIdx.x;
  const int tid = threadIdx.x;
  const int lane = tid & 63, wv = tid >> 6;
  const float* row = pooled + (size_t)bc * II;
  float x0 = row[tid], x1 = row[tid + 256], x2 = row[tid + 512];
  float s = x0 + x1 + x2;
  float sq = x0 * x0 + x1 * x1 + x2 * x2;
  #pragma unroll
  for (int m = 1; m < 64; m <<= 1) { s += __shfl_xor(s, m); sq += __shfl_xor(sq, m); }
  __shared__ float red[8];
  if (lane == 0) { red[wv] = s; red[4 + wv] = sq; }
  __syncthreads();
  s = red[0] + red[1] + red[2] + red[3];
  sq = red[4] + red[5] + red[6] + red[7];
  const float mu = s * (1.0f / 768.0f);
  const float var = sq * (1.0f / 768.0f) - mu * mu;
  const float rs = rsqrtf(var + 1e-5f);
  float dot = ((x0 - mu) * rs * g[tid] + beta[tid]) * Wo[tid]
            + ((x1 - mu) * rs * g[tid + 256] + beta[tid + 256]) * Wo[tid + 256]
            + ((x2 - mu) * rs * g[tid + 512] + beta[tid + 512]) * Wo[tid + 512];
  #pragma unroll
  for (int m = 1; m < 64; m <<= 1) dot += __shfl_xor(dot, m);
  __syncthreads();
  if (lane == 0) red[wv] = dot;
  __syncthreads();
  if (tid == 0) out[bc] = red[0] + red[1] + red[2] + red[3] + bo[0];
}

// ---------------------------------------------------------------------------
extern "C" void kernel_launch(void* const* d_in, const int* in_sizes, int n_in,
                              void* d_out, int out_size, void* d_ws, size_t ws_size,
                              hipStream_t stream) {
  const float* x     = (const float*)d_in[0];   // [B,N,I]
  const int*   amask = (const int*)d_in[1];     // [B,N]
  const float* demb  = (const float*)d_in[2];   // [C,D,I]
  const int*   dmask = (const int*)d_in[3];     // [C,D]
  const float* Wq    = (const float*)d_in[4];
  const float* Wk    = (const float*)d_in[5];
  const float* Wv    = (const float*)d_in[6];
  const float* Wo    = (const float*)d_in[7];   // [1,I]
  const float* bo    = (const float*)d_in[8];   // [1]
  const float* lng   = (const float*)d_in[9];
  const float* lnb   = (const float*)d_in[10];

  char* ws = (char*)d_ws;
  const size_t OFF_Q  = 0;                                      // 16384*768*2
  const size_t OFF_K  = OFF_Q  + (size_t)MM * II * 2;           // 2*2048*768*2
  const size_t OFF_VT = OFF_K  + (size_t)BB * NN * II * 2;      // 2*768*2048*2
  const size_t OFF_LP = OFF_VT + (size_t)BB * II * NN * 2;      // 2*16*16384*4
  const size_t OFF_L  = OFF_LP + (size_t)BB * 16 * MM * 4;      // 2*16384*4
  const size_t OFF_PP = OFF_L  + (size_t)BB * MM * 4;           // 2*256*2048*2
  const size_t OFF_PL = OFF_PP + (size_t)BB * CC * NN * 2;      // 2*256*768*4

  unsigned short* Qp  = (unsigned short*)(ws + OFF_Q);
  unsigned short* Kp  = (unsigned short*)(ws + OFF_K);
  unsigned short* Vt  = (unsigned short*)(ws + OFF_VT);
  float* l_part = (float*)(ws + OFF_LP);
  float* l_ws   = (float*)(ws + OFF_L);
  unsigned short* pp = (unsigned short*)(ws + OFF_PP);
  float* pooled = (float*)(ws + OFF_PL);

  proj_kernel<0><<<dim3(MM / 64, II / 64), 256, 0, stream>>>(demb, Wq, Qp);
  proj_kernel<0><<<dim3((BB * NN) / 64, II / 64), 256, 0, stream>>>(x, Wk, Kp);
  proj_kernel<1><<<dim3((BB * NN) / 64, II / 64), 256, 0, stream>>>(x, Wv, Vt);

  attn_gemm<1><<<dim3(MM / 128, NN / 128, BB), 256, 0, stream>>>(
      Qp, Kp, amask, dmask, nullptr, l_part, nullptr);
  lred_kernel<<<dim3((BB * MM) / 256), 256, 0, stream>>>(l_part, l_ws);
  attn_gemm<2><<<dim3(MM / 128, NN / 128, BB), 256, 0, stream>>>(
      Qp, Kp, amask, dmask, l_ws, nullptr, pp);

  pv_gemm<<<dim3((BB * CC) / 64, II / 64), 256, 0, stream>>>(pp, Vt, pooled);
  ln_out_kernel<<<BB * CC, 256, 0, stream>>>(pooled, lng, lnb, Wo, bo, (float*)d_out);
}

// Round 3
// 283.850 us; speedup vs baseline: 2.9296x; 1.2341x over previous
//
#include <hip/hip_runtime.h>
#include <hip/hip_bf16.h>

#define BB 2
#define NN 2048
#define II 768
#define CC 256
#define DD 64
#define MM (CC * DD)   // 16384 q-rows

typedef __attribute__((ext_vector_type(8))) short short8;
typedef __attribute__((ext_vector_type(4))) float f32x4;

static constexpr float SCALE = 0.036084391824351615f; // 1/sqrt(768)

__device__ __forceinline__ unsigned short f2bf(float f) {
  union { float f; unsigned int u; } v; v.f = f;
  unsigned int u = v.u;
  unsigned int r = u + 0x7fffu + ((u >> 16) & 1u);
  return (unsigned short)(r >> 16);
}
__device__ __forceinline__ float bf2f(unsigned short h) {
  union { unsigned int u; float f; } v; v.u = ((unsigned int)h) << 16;
  return v.f;
}

union U8 { unsigned short us[8]; uint4 v; };

#define GLOAD_LDS16(gp, lp)                                                    \
  __builtin_amdgcn_global_load_lds(                                            \
      (const __attribute__((address_space(1))) unsigned int*)(gp),             \
      (__attribute__((address_space(3))) unsigned int*)(lp), 16, 0, 0)

// ---------------------------------------------------------------------------
// Projection GEMM: out[m][j] = sum_i A[m][i] * W[j][i]  (A,W f32; out bf16).
// 64x64 tile, 4 waves.  MODE 0: out row-major [m][j].
// MODE 1 (V): out transposed Vt[(b*II + j)*NN + n] where m = b*NN + n.
// ---------------------------------------------------------------------------
template <int MODE>
__global__ __launch_bounds__(256, 2)
void proj_kernel(const float* __restrict__ A, const float* __restrict__ W,
                 unsigned short* __restrict__ out)
{
  const int m0 = blockIdx.x * 64;
  const int j0 = blockIdx.y * 64;
  const int tid = threadIdx.x;
  const int lane = tid & 63, wv = tid >> 6;
  const int lrow = lane & 15, khi = lane >> 4;

  __shared__ __align__(16) unsigned short a_lds[64 * 128];
  __shared__ __align__(16) unsigned short w_lds[64 * 128];

  f32x4 acc[4] = {};

  for (int ic = 0; ic < 6; ++ic) {
    __syncthreads();
    #pragma unroll
    for (int u = 0; u < 4; ++u) {
      int idx = u * 256 + tid;          // 1024 groups of 8
      int row = idx >> 4, gp = idx & 15;
      int g = gp ^ (row & 7);           // source group for this (swizzled) slot
      const float* srcA = A + (size_t)(m0 + row) * II + ic * 128 + g * 8;
      const float* srcW = W + (size_t)(j0 + row) * II + ic * 128 + g * 8;
      float4 a0 = *(const float4*)srcA; float4 a1 = *(const float4*)(srcA + 4);
      float4 w0 = *(const float4*)srcW; float4 w1 = *(const float4*)(srcW + 4);
      U8 ua, uw;
      ua.us[0] = f2bf(a0.x); ua.us[1] = f2bf(a0.y); ua.us[2] = f2bf(a0.z); ua.us[3] = f2bf(a0.w);
      ua.us[4] = f2bf(a1.x); ua.us[5] = f2bf(a1.y); ua.us[6] = f2bf(a1.z); ua.us[7] = f2bf(a1.w);
      uw.us[0] = f2bf(w0.x); uw.us[1] = f2bf(w0.y); uw.us[2] = f2bf(w0.z); uw.us[3] = f2bf(w0.w);
      uw.us[4] = f2bf(w1.x); uw.us[5] = f2bf(w1.y); uw.us[6] = f2bf(w1.z); uw.us[7] = f2bf(w1.w);
      *(uint4*)&a_lds[idx * 8] = ua.v;
      *(uint4*)&w_lds[idx * 8] = uw.v;
    }
    __syncthreads();
    #pragma unroll
    for (int s = 0; s < 4; ++s) {       // 4 k-steps of 32 within the 128-chunk
      int g = s * 4 + khi;
      int ar = 16 * wv + lrow;
      short8 af = *(const short8*)&a_lds[(ar * 16 + (g ^ (ar & 7))) * 8];
      #pragma unroll
      for (int f = 0; f < 4; ++f) {
        int br = f * 16 + lrow;
        short8 bfr = *(const short8*)&w_lds[(br * 16 + (g ^ (br & 7))) * 8];
        acc[f] = __builtin_amdgcn_mfma_f32_16x16x32_bf16(af, bfr, acc[f], 0, 0, 0);
      }
    }
  }
  #pragma unroll
  for (int f = 0; f < 4; ++f) {
    #pragma unroll
    for (int r = 0; r < 4; ++r) {
      int row = m0 + 16 * wv + khi * 4 + r;
      int col = j0 + f * 16 + lrow;
      if (MODE == 0) {
        out[(size_t)row * II + col] = f2bf(acc[f][r]);
      } else {
        int bb = row >> 11, n = row & (NN - 1);
        out[((size_t)bb * II + col) * NN + n] = f2bf(acc[f][r]);
      }
    }
  }
}

// ---------------------------------------------------------------------------
// Attention score GEMM, single pass.  S[b][m][n] = sum_i Q[m][i]*K[b][n][i],
// 128x128 tile, BK=64, 4 waves (2x2), global_load_lds w16, XOR-swizzled src.
// Epilogue: P = amask*exp(S*scale) staged bf16 into LDS (XOR-swizzled) then
// vector-stored to global; per-row partials of P -> l_part[b][nt][m].
// ---------------------------------------------------------------------------
__global__ __launch_bounds__(256, 2)
void attn_gemm1(const unsigned short* __restrict__ Qp,
                const unsigned short* __restrict__ Kp,
                const int* __restrict__ amask,
                float* __restrict__ lpart_out,
                unsigned short* __restrict__ P_out)
{
  const int m0 = blockIdx.x * 128;
  const int n0 = blockIdx.y * 128;
  const int b  = blockIdx.z;
  const int tid = threadIdx.x;
  const int lane = tid & 63, wv = tid >> 6;
  const int lrow = lane & 15, khi = lane >> 4;
  const int wr = wv >> 1, wc = wv & 1;

  __shared__ __align__(16) unsigned short smem[128 * 128]; // a|b tiles, then P
  unsigned short* a_lds = smem;              // 128*64
  unsigned short* b_lds = smem + 128 * 64;   // 128*64
  __shared__ float red_lds[128 * 2];

  const unsigned short* Kb = Kp + (size_t)b * NN * II;

  f32x4 acc[4][4] = {};

  for (int kc = 0; kc < 12; ++kc) {
    const int k0 = kc * 64;
    __syncthreads();
    #pragma unroll
    for (int u = 0; u < 4; ++u) {
      int idx = u * 256 + tid;          // 1024 slots of 8 bf16 (16B)
      int row = idx >> 3, g = idx & 7;
      int sg = g ^ (row & 7);
      GLOAD_LDS16(Qp + (size_t)(m0 + row) * II + k0 + sg * 8, &a_lds[idx * 8]);
      GLOAD_LDS16(Kb + (size_t)(n0 + row) * II + k0 + sg * 8, &b_lds[idx * 8]);
    }
    __syncthreads();
    #pragma unroll
    for (int s = 0; s < 2; ++s) {
      short8 af[4], bf[4];
      #pragma unroll
      for (int m = 0; m < 4; ++m) {
        int ar = wr * 64 + m * 16 + lrow;
        int g = s * 4 + khi;
        af[m] = *(const short8*)&a_lds[(ar * 8 + (g ^ (ar & 7))) * 8];
      }
      #pragma unroll
      for (int f = 0; f < 4; ++f) {
        int br = wc * 64 + f * 16 + lrow;
        int g = s * 4 + khi;
        bf[f] = *(const short8*)&b_lds[(br * 8 + (g ^ (br & 7))) * 8];
      }
      #pragma unroll
      for (int m = 0; m < 4; ++m)
        #pragma unroll
        for (int f = 0; f < 4; ++f)
          acc[m][f] = __builtin_amdgcn_mfma_f32_16x16x32_bf16(af[m], bf[f], acc[m][f], 0, 0, 0);
    }
  }

  float msk[4];
  #pragma unroll
  for (int f = 0; f < 4; ++f)
    msk[f] = (amask[b * NN + n0 + wc * 64 + f * 16 + lrow] != 0) ? 1.0f : 0.0f;

  __syncthreads();   // done with a_lds/b_lds; repurpose smem as P tile

  // P tile into smem (bf16, XOR-swizzled cols) + per-row partial sums
  #pragma unroll
  for (int m = 0; m < 4; ++m) {
    #pragma unroll
    for (int r = 0; r < 4; ++r) {
      const int row = wr * 64 + m * 16 + khi * 4 + r;     // 0..127 local
      const int s8 = (row & 7) << 3;
      float rs = 0.0f;
      #pragma unroll
      for (int f = 0; f < 4; ++f) {
        float pe = msk[f] * __expf(acc[m][f][r] * SCALE);
        rs += pe;
        int col = wc * 64 + f * 16 + lrow;
        smem[row * 128 + (col ^ s8)] = f2bf(pe);
      }
      rs += __shfl_xor(rs, 1); rs += __shfl_xor(rs, 2);
      rs += __shfl_xor(rs, 4); rs += __shfl_xor(rs, 8);
      if (lrow == 0) red_lds[row * 2 + wc] = rs;
    }
  }
  __syncthreads();
  if (tid < 128)
    lpart_out[((size_t)(b * 16 + blockIdx.y) << 14) + m0 + tid] =
        red_lds[tid * 2] + red_lds[tid * 2 + 1];
  // coalesced vector store of the P tile
  unsigned short* Pb = P_out + (size_t)b * MM * NN;
  #pragma unroll
  for (int u = 0; u < 8; ++u) {
    int idx = u * 256 + tid;            // 2048 uint4 slots
    int row = idx >> 4, q = idx & 15;
    int gcol = (q ^ (row & 7)) << 3;    // un-swizzled global col group
    *(uint4*)(Pb + (size_t)(m0 + row) * NN + n0 + gcol) =
        *(const uint4*)&smem[row * 128 + q * 8];
  }
}

// ---------------------------------------------------------------------------
// pp[b,c,n] = invdenom_c * sum_d (dmask_d / l_d) * P[b][c*64+d][n]
// One block per (c,b); 256 threads x 8 bf16 = full n-row.  l computed from
// l_part in-kernel (folds the old lred dispatch).
// ---------------------------------------------------------------------------
__global__ __launch_bounds__(256)
void ppred_kernel(const unsigned short* __restrict__ P,
                  const int* __restrict__ dmask,
                  const float* __restrict__ lpart,
                  unsigned short* __restrict__ pp)
{
  const int c = blockIdx.x, b = blockIdx.y;
  const int tid = threadIdx.x;
  __shared__ float wgt[64];
  __shared__ float sinvd;
  if (tid < 64) {
    float dm = (dmask[c * 64 + tid] != 0) ? 1.0f : 0.0f;
    float lv = 0.0f;
    #pragma unroll
    for (int nt = 0; nt < 16; ++nt)
      lv += lpart[(((size_t)(b * 16 + nt)) << 14) + c * 64 + tid];
    float ds = dm;
    #pragma unroll
    for (int m = 1; m < 64; m <<= 1) ds += __shfl_xor(ds, m);
    wgt[tid] = dm / lv;
    if (tid == 0) sinvd = 1.0f / ds;
  }
  __syncthreads();
  const float invd = sinvd;
  float acc[8] = {};
  const unsigned short* Pr = P + ((size_t)b * MM + (size_t)c * 64) * NN + tid * 8;
  #pragma unroll 8
  for (int d = 0; d < 64; ++d) {
    U8 v; v.v = *(const uint4*)(Pr + (size_t)d * NN);
    float w = wgt[d];
    #pragma unroll
    for (int e = 0; e < 8; ++e) acc[e] += w * bf2f(v.us[e]);
  }
  U8 o;
  #pragma unroll
  for (int e = 0; e < 8; ++e) o.us[e] = f2bf(acc[e] * invd);
  *(uint4*)(pp + ((size_t)(b * CC + c)) * NN + tid * 8) = o.v;
}

// ---------------------------------------------------------------------------
// PV GEMM: pooled[mc][j] = sum_n pp[mc][n] * Vt[b*II + j][n]   (f32 out)
// 64x64 tile, 4 waves, K-chunks of 128 over n=2048.
// ---------------------------------------------------------------------------
__global__ __launch_bounds__(256, 2)
void pv_gemm(const unsigned short* __restrict__ pp,
             const unsigned short* __restrict__ Vt,
             float* __restrict__ pooled)
{
  const int m0 = blockIdx.x * 64;
  const int j0 = blockIdx.y * 64;
  const int b  = m0 >> 8;
  const int tid = threadIdx.x;
  const int lane = tid & 63, wv = tid >> 6;
  const int lrow = lane & 15, khi = lane >> 4;

  __shared__ __align__(16) unsigned short a_lds[64 * 128];
  __shared__ __align__(16) unsigned short b_lds[64 * 128];

  f32x4 acc[4] = {};

  for (int kc = 0; kc < 16; ++kc) {
    const int k0 = kc * 128;
    __syncthreads();
    #pragma unroll
    for (int u = 0; u < 4; ++u) {
      int idx = u * 256 + tid;          // 1024 slots of 8 bf16
      int row = idx >> 4, g = idx & 15;
      int sg = g ^ (row & 7);
      GLOAD_LDS16(pp + (size_t)(m0 + row) * NN + k0 + sg * 8, &a_lds[idx * 8]);
      GLOAD_LDS16(Vt + ((size_t)b * II + j0 + row) * NN + k0 + sg * 8, &b_lds[idx * 8]);
    }
    __syncthreads();
    #pragma unroll
    for (int s = 0; s < 4; ++s) {
      int g = s * 4 + khi;
      int ar = 16 * wv + lrow;
      short8 af = *(const short8*)&a_lds[(ar * 16 + (g ^ (ar & 7))) * 8];
      #pragma unroll
      for (int f = 0; f < 4; ++f) {
        int br = f * 16 + lrow;
        short8 bfr = *(const short8*)&b_lds[(br * 16 + (g ^ (br & 7))) * 8];
        acc[f] = __builtin_amdgcn_mfma_f32_16x16x32_bf16(af, bfr, acc[f], 0, 0, 0);
      }
    }
  }
  #pragma unroll
  for (int f = 0; f < 4; ++f)
    #pragma unroll
    for (int r = 0; r < 4; ++r) {
      int row = m0 + 16 * wv + khi * 4 + r;
      int col = j0 + f * 16 + lrow;
      pooled[(size_t)row * II + col] = acc[f][r];
    }
}

// ---------------------------------------------------------------------------
// LayerNorm over i + dot with Wo.  One block per (b,c).
// ---------------------------------------------------------------------------
__global__ __launch_bounds__(256)
void ln_out_kernel(const float* __restrict__ pooled, const float* __restrict__ g,
                   const float* __restrict__ beta, const float* __restrict__ Wo,
                   const float* __restrict__ bo, float* __restrict__ out)
{
  const int bc = blockIdx.x;
  const int tid = threadIdx.x;
  const int lane = tid & 63, wv = tid >> 6;
  const float* row = pooled + (size_t)bc * II;
  float x0 = row[tid], x1 = row[tid + 256], x2 = row[tid + 512];
  float s = x0 + x1 + x2;
  float sq = x0 * x0 + x1 * x1 + x2 * x2;
  #pragma unroll
  for (int m = 1; m < 64; m <<= 1) { s += __shfl_xor(s, m); sq += __shfl_xor(sq, m); }
  __shared__ float red[8];
  if (lane == 0) { red[wv] = s; red[4 + wv] = sq; }
  __syncthreads();
  s = red[0] + red[1] + red[2] + red[3];
  sq = red[4] + red[5] + red[6] + red[7];
  const float mu = s * (1.0f / 768.0f);
  const float var = sq * (1.0f / 768.0f) - mu * mu;
  const float rs = rsqrtf(var + 1e-5f);
  float dot = ((x0 - mu) * rs * g[tid] + beta[tid]) * Wo[tid]
            + ((x1 - mu) * rs * g[tid + 256] + beta[tid + 256]) * Wo[tid + 256]
            + ((x2 - mu) * rs * g[tid + 512] + beta[tid + 512]) * Wo[tid + 512];
  #pragma unroll
  for (int m = 1; m < 64; m <<= 1) dot += __shfl_xor(dot, m);
  __syncthreads();
  if (lane == 0) red[wv] = dot;
  __syncthreads();
  if (tid == 0) out[bc] = red[0] + red[1] + red[2] + red[3] + bo[0];
}

// ---------------------------------------------------------------------------
extern "C" void kernel_launch(void* const* d_in, const int* in_sizes, int n_in,
                              void* d_out, int out_size, void* d_ws, size_t ws_size,
                              hipStream_t stream) {
  const float* x     = (const float*)d_in[0];   // [B,N,I]
  const int*   amask = (const int*)d_in[1];     // [B,N]
  const float* demb  = (const float*)d_in[2];   // [C,D,I]
  const int*   dmask = (const int*)d_in[3];     // [C,D]
  const float* Wq    = (const float*)d_in[4];
  const float* Wk    = (const float*)d_in[5];
  const float* Wv    = (const float*)d_in[6];
  const float* Wo    = (const float*)d_in[7];   // [1,I]
  const float* bo    = (const float*)d_in[8];   // [1]
  const float* lng   = (const float*)d_in[9];
  const float* lnb   = (const float*)d_in[10];

  char* ws = (char*)d_ws;
  const size_t OFF_Q  = 0;                                      // 24 MB
  const size_t OFF_K  = OFF_Q  + (size_t)MM * II * 2;           // 6 MB
  const size_t OFF_VT = OFF_K  + (size_t)BB * NN * II * 2;      // 6 MB
  const size_t OFF_LP = OFF_VT + (size_t)BB * II * NN * 2;      // 4 MB
  const size_t OFF_PP = OFF_LP + (size_t)BB * 16 * MM * 4;      // 2 MB
  const size_t OFF_PL = OFF_PP + (size_t)BB * CC * NN * 2;      // 1.5 MB
  const size_t OFF_P  = OFF_PL + (size_t)BB * CC * II * 4;      // 128 MB

  unsigned short* Qp  = (unsigned short*)(ws + OFF_Q);
  unsigned short* Kp  = (unsigned short*)(ws + OFF_K);
  unsigned short* Vt  = (unsigned short*)(ws + OFF_VT);
  float* l_part = (float*)(ws + OFF_LP);
  unsigned short* pp = (unsigned short*)(ws + OFF_PP);
  float* pooled = (float*)(ws + OFF_PL);
  unsigned short* P  = (unsigned short*)(ws + OFF_P);

  proj_kernel<0><<<dim3(MM / 64, II / 64), 256, 0, stream>>>(demb, Wq, Qp);
  proj_kernel<0><<<dim3((BB * NN) / 64, II / 64), 256, 0, stream>>>(x, Wk, Kp);
  proj_kernel<1><<<dim3((BB * NN) / 64, II / 64), 256, 0, stream>>>(x, Wv, Vt);

  attn_gemm1<<<dim3(MM / 128, NN / 128, BB), 256, 0, stream>>>(
      Qp, Kp, amask, l_part, P);
  ppred_kernel<<<dim3(CC, BB), 256, 0, stream>>>(P, dmask, l_part, pp);

  pv_gemm<<<dim3((BB * CC) / 64, II / 64), 256, 0, stream>>>(pp, Vt, pooled);
  ln_out_kernel<<<BB * CC, 256, 0, stream>>>(pooled, lng, lnb, Wo, bo, (float*)d_out);
}

// Round 4
// 228.549 us; speedup vs baseline: 3.6384x; 1.2420x over previous
//
#include <hip/hip_runtime.h>
#include <hip/hip_bf16.h>

#define BB 2
#define NN 2048
#define II 768
#define CC 256
#define DD 64
#define MM (CC * DD)   // 16384 q-rows

typedef __attribute__((ext_vector_type(8))) short short8;
typedef __attribute__((ext_vector_type(4))) float f32x4;

static constexpr float SCALE = 0.036084391824351615f; // 1/sqrt(768)

__device__ __forceinline__ unsigned short f2bf(float f) {
  union { float f; unsigned int u; } v; v.f = f;
  unsigned int u = v.u;
  unsigned int r = u + 0x7fffu + ((u >> 16) & 1u);
  return (unsigned short)(r >> 16);
}
__device__ __forceinline__ float bf2f(unsigned short h) {
  union { unsigned int u; float f; } v; v.u = ((unsigned int)h) << 16;
  return v.f;
}

union U8 { unsigned short us[8]; uint4 v; };
struct US4 { unsigned short x, y, z, w; };

#define GLOAD_LDS16(gp, lp)                                                    \
  __builtin_amdgcn_global_load_lds(                                            \
      (const __attribute__((address_space(1))) unsigned int*)(gp),             \
      (__attribute__((address_space(3))) unsigned int*)(lp), 16, 0, 0)

// ---------------------------------------------------------------------------
// f32 -> bf16 bulk conversion of all GEMM operands (grid-stride, float4).
// ---------------------------------------------------------------------------
__global__ __launch_bounds__(256)
void cvt_kernel(const float* __restrict__ demb, const float* __restrict__ x,
                const float* __restrict__ Wq, const float* __restrict__ Wk,
                const float* __restrict__ Wv,
                unsigned short* __restrict__ Qb, unsigned short* __restrict__ xb,
                unsigned short* __restrict__ Wqb, unsigned short* __restrict__ Wkb,
                unsigned short* __restrict__ Wvb)
{
  const int NF_DEMB = 3145728;          // 12.58M elems /4
  const int NF_X    = 786432;
  const int NF_W    = 147456;
  const int NF_TOT  = NF_DEMB + NF_X + 3 * NF_W;
  for (int i = blockIdx.x * 256 + threadIdx.x; i < NF_TOT; i += gridDim.x * 256) {
    const float* src; unsigned short* dst; int off;
    if (i < NF_DEMB) { src = demb; dst = Qb; off = i; }
    else if (i < NF_DEMB + NF_X) { src = x; dst = xb; off = i - NF_DEMB; }
    else if (i < NF_DEMB + NF_X + NF_W) { src = Wq; dst = Wqb; off = i - NF_DEMB - NF_X; }
    else if (i < NF_DEMB + NF_X + 2 * NF_W) { src = Wk; dst = Wkb; off = i - NF_DEMB - NF_X - NF_W; }
    else { src = Wv; dst = Wvb; off = i - NF_DEMB - NF_X - 2 * NF_W; }
    float4 v = *(const float4*)(src + (size_t)off * 4);
    US4 o; o.x = f2bf(v.x); o.y = f2bf(v.y); o.z = f2bf(v.z); o.w = f2bf(v.w);
    *(US4*)(dst + (size_t)off * 4) = o;
  }
}

// ---------------------------------------------------------------------------
// bf16 projection GEMM: out[m][j] = sum_i A[m][i]*W[j][i], 128x128 tile,
// BK=64, 4 waves (2x2), global_load_lds w16, XOR-swizzled source.
// MODE 0: out row-major bf16 [m][II] (LDS-staged coalesced store).
// MODE 1: out transposed Vt[(b*II+j)*NN + n], m = b*NN + n (scalar stores).
// ---------------------------------------------------------------------------
template <int MODE>
__global__ __launch_bounds__(256, 2)
void proj128(const unsigned short* __restrict__ A,
             const unsigned short* __restrict__ W,
             unsigned short* __restrict__ out)
{
  const int m0 = blockIdx.x * 128;
  const int j0 = blockIdx.y * 128;
  const int tid = threadIdx.x;
  const int lane = tid & 63, wv = tid >> 6;
  const int lrow = lane & 15, khi = lane >> 4;
  const int wr = wv >> 1, wc = wv & 1;

  __shared__ __align__(16) unsigned short smem[128 * 128];
  unsigned short* a_lds = smem;              // 128*64
  unsigned short* b_lds = smem + 128 * 64;   // 128*64

  f32x4 acc[4][4] = {};

  for (int kc = 0; kc < 12; ++kc) {
    const int k0 = kc * 64;
    __syncthreads();
    #pragma unroll
    for (int u = 0; u < 4; ++u) {
      int idx = u * 256 + tid;          // 1024 slots of 8 bf16 (16B)
      int row = idx >> 3, g = idx & 7;
      int sg = g ^ (row & 7);
      GLOAD_LDS16(A + (size_t)(m0 + row) * II + k0 + sg * 8, &a_lds[idx * 8]);
      GLOAD_LDS16(W + (size_t)(j0 + row) * II + k0 + sg * 8, &b_lds[idx * 8]);
    }
    __syncthreads();
    #pragma unroll
    for (int s = 0; s < 2; ++s) {
      short8 af[4], bf[4];
      #pragma unroll
      for (int m = 0; m < 4; ++m) {
        int ar = wr * 64 + m * 16 + lrow;
        int g = s * 4 + khi;
        af[m] = *(const short8*)&a_lds[(ar * 8 + (g ^ (ar & 7))) * 8];
      }
      #pragma unroll
      for (int f = 0; f < 4; ++f) {
        int br = wc * 64 + f * 16 + lrow;
        int g = s * 4 + khi;
        bf[f] = *(const short8*)&b_lds[(br * 8 + (g ^ (br & 7))) * 8];
      }
      #pragma unroll
      for (int m = 0; m < 4; ++m)
        #pragma unroll
        for (int f = 0; f < 4; ++f)
          acc[m][f] = __builtin_amdgcn_mfma_f32_16x16x32_bf16(af[m], bf[f], acc[m][f], 0, 0, 0);
    }
  }

  if (MODE == 0) {
    __syncthreads();   // repurpose smem as 128x128 bf16 C tile
    #pragma unroll
    for (int m = 0; m < 4; ++m) {
      #pragma unroll
      for (int r = 0; r < 4; ++r) {
        const int row = wr * 64 + m * 16 + khi * 4 + r;   // local 0..127
        const int s8 = (row & 7) << 3;
        #pragma unroll
        for (int f = 0; f < 4; ++f) {
          int col = wc * 64 + f * 16 + lrow;
          smem[row * 128 + (col ^ s8)] = f2bf(acc[m][f][r]);
        }
      }
    }
    __syncthreads();
    #pragma unroll
    for (int u = 0; u < 8; ++u) {
      int idx = u * 256 + tid;          // 2048 uint4 slots
      int row = idx >> 4, q = idx & 15;
      int gcol = (q ^ (row & 7)) << 3;
      *(uint4*)(out + (size_t)(m0 + row) * II + j0 + gcol) =
          *(const uint4*)&smem[row * 128 + q * 8];
    }
  } else {
    #pragma unroll
    for (int m = 0; m < 4; ++m)
      #pragma unroll
      for (int f = 0; f < 4; ++f)
        #pragma unroll
        for (int r = 0; r < 4; ++r) {
          int row = m0 + wr * 64 + m * 16 + khi * 4 + r;
          int col = j0 + wc * 64 + f * 16 + lrow;
          int bb = row >> 11, n = row & (NN - 1);
          out[((size_t)bb * II + col) * NN + n] = f2bf(acc[m][f][r]);
        }
  }
}

// ---------------------------------------------------------------------------
// Attention score GEMM, single pass.  S[b][m][n] = sum_i Q[m][i]*K[b][n][i],
// 128x128 tile, BK=64, 4 waves (2x2), global_load_lds w16, XOR-swizzled src.
// Epilogue: P = amask*exp(S*scale) staged bf16 into LDS (XOR-swizzled) then
// vector-stored to global; per-row partials of P -> l_part[b][nt][m].
// ---------------------------------------------------------------------------
__global__ __launch_bounds__(256, 2)
void attn_gemm1(const unsigned short* __restrict__ Qp,
                const unsigned short* __restrict__ Kp,
                const int* __restrict__ amask,
                float* __restrict__ lpart_out,
                unsigned short* __restrict__ P_out)
{
  const int m0 = blockIdx.x * 128;
  const int n0 = blockIdx.y * 128;
  const int b  = blockIdx.z;
  const int tid = threadIdx.x;
  const int lane = tid & 63, wv = tid >> 6;
  const int lrow = lane & 15, khi = lane >> 4;
  const int wr = wv >> 1, wc = wv & 1;

  __shared__ __align__(16) unsigned short smem[128 * 128]; // a|b tiles, then P
  unsigned short* a_lds = smem;              // 128*64
  unsigned short* b_lds = smem + 128 * 64;   // 128*64
  __shared__ float red_lds[128 * 2];

  const unsigned short* Kb = Kp + (size_t)b * NN * II;

  f32x4 acc[4][4] = {};

  for (int kc = 0; kc < 12; ++kc) {
    const int k0 = kc * 64;
    __syncthreads();
    #pragma unroll
    for (int u = 0; u < 4; ++u) {
      int idx = u * 256 + tid;          // 1024 slots of 8 bf16 (16B)
      int row = idx >> 3, g = idx & 7;
      int sg = g ^ (row & 7);
      GLOAD_LDS16(Qp + (size_t)(m0 + row) * II + k0 + sg * 8, &a_lds[idx * 8]);
      GLOAD_LDS16(Kb + (size_t)(n0 + row) * II + k0 + sg * 8, &b_lds[idx * 8]);
    }
    __syncthreads();
    #pragma unroll
    for (int s = 0; s < 2; ++s) {
      short8 af[4], bf[4];
      #pragma unroll
      for (int m = 0; m < 4; ++m) {
        int ar = wr * 64 + m * 16 + lrow;
        int g = s * 4 + khi;
        af[m] = *(const short8*)&a_lds[(ar * 8 + (g ^ (ar & 7))) * 8];
      }
      #pragma unroll
      for (int f = 0; f < 4; ++f) {
        int br = wc * 64 + f * 16 + lrow;
        int g = s * 4 + khi;
        bf[f] = *(const short8*)&b_lds[(br * 8 + (g ^ (br & 7))) * 8];
      }
      #pragma unroll
      for (int m = 0; m < 4; ++m)
        #pragma unroll
        for (int f = 0; f < 4; ++f)
          acc[m][f] = __builtin_amdgcn_mfma_f32_16x16x32_bf16(af[m], bf[f], acc[m][f], 0, 0, 0);
    }
  }

  float msk[4];
  #pragma unroll
  for (int f = 0; f < 4; ++f)
    msk[f] = (amask[b * NN + n0 + wc * 64 + f * 16 + lrow] != 0) ? 1.0f : 0.0f;

  __syncthreads();   // done with a_lds/b_lds; repurpose smem as P tile

  // P tile into smem (bf16, XOR-swizzled cols) + per-row partial sums
  #pragma unroll
  for (int m = 0; m < 4; ++m) {
    #pragma unroll
    for (int r = 0; r < 4; ++r) {
      const int row = wr * 64 + m * 16 + khi * 4 + r;     // 0..127 local
      const int s8 = (row & 7) << 3;
      float rs = 0.0f;
      #pragma unroll
      for (int f = 0; f < 4; ++f) {
        float pe = msk[f] * __expf(acc[m][f][r] * SCALE);
        rs += pe;
        int col = wc * 64 + f * 16 + lrow;
        smem[row * 128 + (col ^ s8)] = f2bf(pe);
      }
      rs += __shfl_xor(rs, 1); rs += __shfl_xor(rs, 2);
      rs += __shfl_xor(rs, 4); rs += __shfl_xor(rs, 8);
      if (lrow == 0) red_lds[row * 2 + wc] = rs;
    }
  }
  __syncthreads();
  if (tid < 128)
    lpart_out[((size_t)(b * 16 + blockIdx.y) << 14) + m0 + tid] =
        red_lds[tid * 2] + red_lds[tid * 2 + 1];
  // coalesced vector store of the P tile
  unsigned short* Pb = P_out + (size_t)b * MM * NN;
  #pragma unroll
  for (int u = 0; u < 8; ++u) {
    int idx = u * 256 + tid;            // 2048 uint4 slots
    int row = idx >> 4, q = idx & 15;
    int gcol = (q ^ (row & 7)) << 3;    // un-swizzled global col group
    *(uint4*)(Pb + (size_t)(m0 + row) * NN + n0 + gcol) =
        *(const uint4*)&smem[row * 128 + q * 8];
  }
}

// ---------------------------------------------------------------------------
// pp[b,c,n] = invdenom_c * sum_d (dmask_d / l_d) * P[b][c*64+d][n]
// One block per (c,b); 256 threads x 8 bf16 = full n-row.  l computed from
// l_part in-kernel.
// ---------------------------------------------------------------------------
__global__ __launch_bounds__(256)
void ppred_kernel(const unsigned short* __restrict__ P,
                  const int* __restrict__ dmask,
                  const float* __restrict__ lpart,
                  unsigned short* __restrict__ pp)
{
  const int c = blockIdx.x, b = blockIdx.y;
  const int tid = threadIdx.x;
  __shared__ float wgt[64];
  __shared__ float sinvd;
  if (tid < 64) {
    float dm = (dmask[c * 64 + tid] != 0) ? 1.0f : 0.0f;
    float lv = 0.0f;
    #pragma unroll
    for (int nt = 0; nt < 16; ++nt)
      lv += lpart[(((size_t)(b * 16 + nt)) << 14) + c * 64 + tid];
    float ds = dm;
    #pragma unroll
    for (int m = 1; m < 64; m <<= 1) ds += __shfl_xor(ds, m);
    wgt[tid] = dm / lv;
    if (tid == 0) sinvd = 1.0f / ds;
  }
  __syncthreads();
  const float invd = sinvd;
  float acc[8] = {};
  const unsigned short* Pr = P + ((size_t)b * MM + (size_t)c * 64) * NN + tid * 8;
  #pragma unroll 8
  for (int d = 0; d < 64; ++d) {
    U8 v; v.v = *(const uint4*)(Pr + (size_t)d * NN);
    float w = wgt[d];
    #pragma unroll
    for (int e = 0; e < 8; ++e) acc[e] += w * bf2f(v.us[e]);
  }
  U8 o;
  #pragma unroll
  for (int e = 0; e < 8; ++e) o.us[e] = f2bf(acc[e] * invd);
  *(uint4*)(pp + ((size_t)(b * CC + c)) * NN + tid * 8) = o.v;
}

// ---------------------------------------------------------------------------
// PV GEMM: pooled[mc][j] = sum_n pp[mc][n] * Vt[b*II + j][n]   (f32 out)
// 64x64 tile, 4 waves, K-chunks of 128 over n=2048.
// ---------------------------------------------------------------------------
__global__ __launch_bounds__(256, 2)
void pv_gemm(const unsigned short* __restrict__ pp,
             const unsigned short* __restrict__ Vt,
             float* __restrict__ pooled)
{
  const int m0 = blockIdx.x * 64;
  const int j0 = blockIdx.y * 64;
  const int b  = m0 >> 8;
  const int tid = threadIdx.x;
  const int lane = tid & 63, wv = tid >> 6;
  const int lrow = lane & 15, khi = lane >> 4;

  __shared__ __align__(16) unsigned short a_lds[64 * 128];
  __shared__ __align__(16) unsigned short b_lds[64 * 128];

  f32x4 acc[4] = {};

  for (int kc = 0; kc < 16; ++kc) {
    const int k0 = kc * 128;
    __syncthreads();
    #pragma unroll
    for (int u = 0; u < 4; ++u) {
      int idx = u * 256 + tid;          // 1024 slots of 8 bf16
      int row = idx >> 4, g = idx & 15;
      int sg = g ^ (row & 7);
      GLOAD_LDS16(pp + (size_t)(m0 + row) * NN + k0 + sg * 8, &a_lds[idx * 8]);
      GLOAD_LDS16(Vt + ((size_t)b * II + j0 + row) * NN + k0 + sg * 8, &b_lds[idx * 8]);
    }
    __syncthreads();
    #pragma unroll
    for (int s = 0; s < 4; ++s) {
      int g = s * 4 + khi;
      int ar = 16 * wv + lrow;
      short8 af = *(const short8*)&a_lds[(ar * 16 + (g ^ (ar & 7))) * 8];
      #pragma unroll
      for (int f = 0; f < 4; ++f) {
        int br = f * 16 + lrow;
        short8 bfr = *(const short8*)&b_lds[(br * 16 + (g ^ (br & 7))) * 8];
        acc[f] = __builtin_amdgcn_mfma_f32_16x16x32_bf16(af, bfr, acc[f], 0, 0, 0);
      }
    }
  }
  #pragma unroll
  for (int f = 0; f < 4; ++f)
    #pragma unroll
    for (int r = 0; r < 4; ++r) {
      int row = m0 + 16 * wv + khi * 4 + r;
      int col = j0 + f * 16 + lrow;
      pooled[(size_t)row * II + col] = acc[f][r];
    }
}

// ---------------------------------------------------------------------------
// LayerNorm over i + dot with Wo.  One block per (b,c).
// ---------------------------------------------------------------------------
__global__ __launch_bounds__(256)
void ln_out_kernel(const float* __restrict__ pooled, const float* __restrict__ g,
                   const float* __restrict__ beta, const float* __restrict__ Wo,
                   const float* __restrict__ bo, float* __restrict__ out)
{
  const int bc = blockIdx.x;
  const int tid = threadIdx.x;
  const int lane = tid & 63, wv = tid >> 6;
  const float* row = pooled + (size_t)bc * II;
  float x0 = row[tid], x1 = row[tid + 256], x2 = row[tid + 512];
  float s = x0 + x1 + x2;
  float sq = x0 * x0 + x1 * x1 + x2 * x2;
  #pragma unroll
  for (int m = 1; m < 64; m <<= 1) { s += __shfl_xor(s, m); sq += __shfl_xor(sq, m); }
  __shared__ float red[8];
  if (lane == 0) { red[wv] = s; red[4 + wv] = sq; }
  __syncthreads();
  s = red[0] + red[1] + red[2] + red[3];
  sq = red[4] + red[5] + red[6] + red[7];
  const float mu = s * (1.0f / 768.0f);
  const float var = sq * (1.0f / 768.0f) - mu * mu;
  const float rs = rsqrtf(var + 1e-5f);
  float dot = ((x0 - mu) * rs * g[tid] + beta[tid]) * Wo[tid]
            + ((x1 - mu) * rs * g[tid + 256] + beta[tid + 256]) * Wo[tid + 256]
            + ((x2 - mu) * rs * g[tid + 512] + beta[tid + 512]) * Wo[tid + 512];
  #pragma unroll
  for (int m = 1; m < 64; m <<= 1) dot += __shfl_xor(dot, m);
  __syncthreads();
  if (lane == 0) red[wv] = dot;
  __syncthreads();
  if (tid == 0) out[bc] = red[0] + red[1] + red[2] + red[3] + bo[0];
}

// ---------------------------------------------------------------------------
extern "C" void kernel_launch(void* const* d_in, const int* in_sizes, int n_in,
                              void* d_out, int out_size, void* d_ws, size_t ws_size,
                              hipStream_t stream) {
  const float* x     = (const float*)d_in[0];   // [B,N,I]
  const int*   amask = (const int*)d_in[1];     // [B,N]
  const float* demb  = (const float*)d_in[2];   // [C,D,I]
  const int*   dmask = (const int*)d_in[3];     // [C,D]
  const float* Wq    = (const float*)d_in[4];
  const float* Wk    = (const float*)d_in[5];
  const float* Wv    = (const float*)d_in[6];
  const float* Wo    = (const float*)d_in[7];   // [1,I]
  const float* bo    = (const float*)d_in[8];   // [1]
  const float* lng   = (const float*)d_in[9];
  const float* lnb   = (const float*)d_in[10];

  char* ws = (char*)d_ws;
  // Region A (0 .. 134.2MB): conversion buffers, later overwritten by P.
  // (conv buffers are fully consumed by the proj GEMMs before attn runs.)
  const size_t OFF_QB  = 0;                                   // 25.2 MB
  const size_t OFF_XB  = OFF_QB + (size_t)MM * II * 2;        // 6.3 MB
  const size_t OFF_WQB = OFF_XB + (size_t)BB * NN * II * 2;   // 1.2 MB
  const size_t OFF_WKB = OFF_WQB + (size_t)II * II * 2;
  const size_t OFF_WVB = OFF_WKB + (size_t)II * II * 2;
  const size_t OFF_P   = 0;                                   // 134.2 MB
  // Region B (after P):
  const size_t OFF_QP = (size_t)BB * MM * NN * 2;             // 25.2 MB
  const size_t OFF_KP = OFF_QP + (size_t)MM * II * 2;         // 6.3 MB
  const size_t OFF_VT = OFF_KP + (size_t)BB * NN * II * 2;    // 6.3 MB
  const size_t OFF_LP = OFF_VT + (size_t)BB * II * NN * 2;    // 2.1 MB
  const size_t OFF_PP = OFF_LP + (size_t)BB * 16 * MM * 4;    // 2.1 MB
  const size_t OFF_PL = OFF_PP + (size_t)BB * CC * NN * 2;    // 1.6 MB

  unsigned short* Qb  = (unsigned short*)(ws + OFF_QB);
  unsigned short* xb  = (unsigned short*)(ws + OFF_XB);
  unsigned short* Wqb = (unsigned short*)(ws + OFF_WQB);
  unsigned short* Wkb = (unsigned short*)(ws + OFF_WKB);
  unsigned short* Wvb = (unsigned short*)(ws + OFF_WVB);
  unsigned short* P   = (unsigned short*)(ws + OFF_P);
  unsigned short* Qp  = (unsigned short*)(ws + OFF_QP);
  unsigned short* Kp  = (unsigned short*)(ws + OFF_KP);
  unsigned short* Vt  = (unsigned short*)(ws + OFF_VT);
  float* l_part = (float*)(ws + OFF_LP);
  unsigned short* pp = (unsigned short*)(ws + OFF_PP);
  float* pooled = (float*)(ws + OFF_PL);

  cvt_kernel<<<2048, 256, 0, stream>>>(demb, x, Wq, Wk, Wv, Qb, xb, Wqb, Wkb, Wvb);

  proj128<0><<<dim3(MM / 128, II / 128), 256, 0, stream>>>(Qb, Wqb, Qp);
  proj128<0><<<dim3((BB * NN) / 128, II / 128), 256, 0, stream>>>(xb, Wkb, Kp);
  proj128<1><<<dim3((BB * NN) / 128, II / 128), 256, 0, stream>>>(xb, Wvb, Vt);

  attn_gemm1<<<dim3(MM / 128, NN / 128, BB), 256, 0, stream>>>(
      Qp, Kp, amask, l_part, P);
  ppred_kernel<<<dim3(CC, BB), 256, 0, stream>>>(P, dmask, l_part, pp);

  pv_gemm<<<dim3((BB * CC) / 64, II / 64), 256, 0, stream>>>(pp, Vt, pooled);
  ln_out_kernel<<<BB * CC, 256, 0, stream>>>(pooled, lng, lnb, Wo, bo, (float*)d_out);
}

// Round 5
// 184.605 us; speedup vs baseline: 4.5045x; 1.2380x over previous
//
#include <hip/hip_runtime.h>
#include <hip/hip_bf16.h>

#define BB 2
#define NN 2048
#define II 768
#define CC 256
#define DD 64
#define MM (CC * DD)   // 16384 q-rows (worst case)

typedef __attribute__((ext_vector_type(8))) short short8;
typedef __attribute__((ext_vector_type(4))) float f32x4;

static constexpr float SCALE = 0.036084391824351615f; // 1/sqrt(768)

__device__ __forceinline__ unsigned short f2bf(float f) {
  union { float f; unsigned int u; } v; v.f = f;
  unsigned int u = v.u;
  unsigned int r = u + 0x7fffu + ((u >> 16) & 1u);
  return (unsigned short)(r >> 16);
}
__device__ __forceinline__ float bf2f(unsigned short h) {
  union { unsigned int u; float f; } v; v.u = ((unsigned int)h) << 16;
  return v.f;
}

union U8 { unsigned short us[8]; uint4 v; };
struct US4 { unsigned short x, y, z, w; };

#define GLOAD_LDS16(gp, lp)                                                    \
  __builtin_amdgcn_global_load_lds(                                            \
      (const __attribute__((address_space(1))) unsigned int*)(gp),             \
      (__attribute__((address_space(3))) unsigned int*)(lp), 16, 0, 0)

// ---------------------------------------------------------------------------
// Valid-row compaction: idx[r] = global row (c*64+d) of r-th valid desc token,
// cstart[c]/ccnt[c] per class, meta[0] = Mpad (Mv rounded up to 128).
// Single block, 256 threads (one per class), Hillis-Steele scan in LDS.
// ---------------------------------------------------------------------------
__global__ __launch_bounds__(256)
void scan_kernel(const int* __restrict__ dmask, int* __restrict__ idx,
                 int* __restrict__ cstart, int* __restrict__ ccnt,
                 int* __restrict__ meta)
{
  const int c = threadIdx.x;
  int4 dmv[16];
  const int4* src = (const int4*)(dmask + c * 64);
  int cnt = 0;
  #pragma unroll
  for (int u = 0; u < 16; ++u) {
    dmv[u] = src[u];
    cnt += (dmv[u].x != 0) + (dmv[u].y != 0) + (dmv[u].z != 0) + (dmv[u].w != 0);
  }
  __shared__ int s[256];
  s[c] = cnt;
  __syncthreads();
  for (int off = 1; off < 256; off <<= 1) {
    int v = (c >= off) ? s[c - off] : 0;
    __syncthreads();
    s[c] += v;
    __syncthreads();
  }
  const int excl = s[c] - cnt;
  cstart[c] = excl;
  ccnt[c] = cnt;
  int j = excl;
  #pragma unroll
  for (int u = 0; u < 16; ++u) {
    if (dmv[u].x) idx[j++] = c * 64 + u * 4 + 0;
    if (dmv[u].y) idx[j++] = c * 64 + u * 4 + 1;
    if (dmv[u].z) idx[j++] = c * 64 + u * 4 + 2;
    if (dmv[u].w) idx[j++] = c * 64 + u * 4 + 3;
  }
  if (c == 255) {
    int mv = s[255];
    int mpad = (mv + 127) & ~127;
    for (int t = mv; t < mpad; ++t) idx[t] = 0;  // pad -> row 0 (valid), ignored
    meta[0] = mpad;
  }
}

// ---------------------------------------------------------------------------
// f32 -> bf16 bulk conversion of all GEMM operands (grid-stride, float4).
// demb rows with dmask==0 are skipped entirely (never read downstream).
// ---------------------------------------------------------------------------
__global__ __launch_bounds__(256)
void cvt_kernel(const float* __restrict__ demb, const float* __restrict__ x,
                const float* __restrict__ Wq, const float* __restrict__ Wk,
                const float* __restrict__ Wv, const int* __restrict__ dmask,
                unsigned short* __restrict__ Qb, unsigned short* __restrict__ xb,
                unsigned short* __restrict__ Wqb, unsigned short* __restrict__ Wkb,
                unsigned short* __restrict__ Wvb)
{
  const int NF_DEMB = 3145728;          // 12.58M elems /4
  const int NF_X    = 786432;
  const int NF_W    = 147456;
  const int NF_TOT  = NF_DEMB + NF_X + 3 * NF_W;
  for (int i = blockIdx.x * 256 + threadIdx.x; i < NF_TOT; i += gridDim.x * 256) {
    const float* src; unsigned short* dst; int off;
    if (i < NF_DEMB) {
      if (dmask[i / 192] == 0) continue;   // 192 float4-groups per row
      src = demb; dst = Qb; off = i;
    }
    else if (i < NF_DEMB + NF_X) { src = x; dst = xb; off = i - NF_DEMB; }
    else if (i < NF_DEMB + NF_X + NF_W) { src = Wq; dst = Wqb; off = i - NF_DEMB - NF_X; }
    else if (i < NF_DEMB + NF_X + 2 * NF_W) { src = Wk; dst = Wkb; off = i - NF_DEMB - NF_X - NF_W; }
    else { src = Wv; dst = Wvb; off = i - NF_DEMB - NF_X - 2 * NF_W; }
    float4 v = *(const float4*)(src + (size_t)off * 4);
    US4 o; o.x = f2bf(v.x); o.y = f2bf(v.y); o.z = f2bf(v.z); o.w = f2bf(v.w);
    *(US4*)(dst + (size_t)off * 4) = o;
  }
}

// ---------------------------------------------------------------------------
// bf16 projection GEMM: out[m][j] = sum_i A[m][i]*W[j][i], 128x128 tile,
// BK=64, 4 waves (2x2), global_load_lds w16, XOR-swizzled source.
// GATHER: A-rows remapped through gidx (compacted Q); early-exit at Mpad.
// MODE 0: out row-major bf16 [m][II].  MODE 1: out transposed Vt.
// ---------------------------------------------------------------------------
template <int MODE, int GATHER>
__global__ __launch_bounds__(256, 2)
void proj128(const unsigned short* __restrict__ A,
             const unsigned short* __restrict__ W,
             unsigned short* __restrict__ out,
             const int* __restrict__ gidx, const int* __restrict__ meta)
{
  const int m0 = blockIdx.x * 128;
  if (GATHER) { if (m0 >= meta[0]) return; }
  const int j0 = blockIdx.y * 128;
  const int tid = threadIdx.x;
  const int lane = tid & 63, wv = tid >> 6;
  const int lrow = lane & 15, khi = lane >> 4;
  const int wr = wv >> 1, wc = wv & 1;

  __shared__ __align__(16) unsigned short smem[128 * 128];
  unsigned short* a_lds = smem;              // 128*64
  unsigned short* b_lds = smem + 128 * 64;   // 128*64

  int rowsrc[4];
  #pragma unroll
  for (int u = 0; u < 4; ++u) {
    int row = (u * 256 + tid) >> 3;
    rowsrc[u] = GATHER ? gidx[m0 + row] : (m0 + row);
  }

  f32x4 acc[4][4] = {};

  for (int kc = 0; kc < 12; ++kc) {
    const int k0 = kc * 64;
    __syncthreads();
    #pragma unroll
    for (int u = 0; u < 4; ++u) {
      int idx = u * 256 + tid;          // 1024 slots of 8 bf16 (16B)
      int row = idx >> 3, g = idx & 7;
      int sg = g ^ (row & 7);
      GLOAD_LDS16(A + (size_t)rowsrc[u] * II + k0 + sg * 8, &a_lds[idx * 8]);
      GLOAD_LDS16(W + (size_t)(j0 + row) * II + k0 + sg * 8, &b_lds[idx * 8]);
    }
    __syncthreads();
    #pragma unroll
    for (int s = 0; s < 2; ++s) {
      short8 af[4], bf[4];
      #pragma unroll
      for (int m = 0; m < 4; ++m) {
        int ar = wr * 64 + m * 16 + lrow;
        int g = s * 4 + khi;
        af[m] = *(const short8*)&a_lds[(ar * 8 + (g ^ (ar & 7))) * 8];
      }
      #pragma unroll
      for (int f = 0; f < 4; ++f) {
        int br = wc * 64 + f * 16 + lrow;
        int g = s * 4 + khi;
        bf[f] = *(const short8*)&b_lds[(br * 8 + (g ^ (br & 7))) * 8];
      }
      #pragma unroll
      for (int m = 0; m < 4; ++m)
        #pragma unroll
        for (int f = 0; f < 4; ++f)
          acc[m][f] = __builtin_amdgcn_mfma_f32_16x16x32_bf16(af[m], bf[f], acc[m][f], 0, 0, 0);
    }
  }

  if (MODE == 0) {
    __syncthreads();   // repurpose smem as 128x128 bf16 C tile
    #pragma unroll
    for (int m = 0; m < 4; ++m) {
      #pragma unroll
      for (int r = 0; r < 4; ++r) {
        const int row = wr * 64 + m * 16 + khi * 4 + r;   // local 0..127
        const int s8 = (row & 7) << 3;
        #pragma unroll
        for (int f = 0; f < 4; ++f) {
          int col = wc * 64 + f * 16 + lrow;
          smem[row * 128 + (col ^ s8)] = f2bf(acc[m][f][r]);
        }
      }
    }
    __syncthreads();
    #pragma unroll
    for (int u = 0; u < 8; ++u) {
      int idx = u * 256 + tid;          // 2048 uint4 slots
      int row = idx >> 4, q = idx & 15;
      int gcol = (q ^ (row & 7)) << 3;
      *(uint4*)(out + (size_t)(m0 + row) * II + j0 + gcol) =
          *(const uint4*)&smem[row * 128 + q * 8];
    }
  } else {
    #pragma unroll
    for (int m = 0; m < 4; ++m)
      #pragma unroll
      for (int f = 0; f < 4; ++f)
        #pragma unroll
        for (int r = 0; r < 4; ++r) {
          int row = m0 + wr * 64 + m * 16 + khi * 4 + r;
          int col = j0 + wc * 64 + f * 16 + lrow;
          int bb = row >> 11, n = row & (NN - 1);
          out[((size_t)bb * II + col) * NN + n] = f2bf(acc[m][f][r]);
        }
  }
}

// ---------------------------------------------------------------------------
// Attention score GEMM over COMPACT rows.  S[b][r][n] = sum_i Q[r][i]*K[b][n][i]
// 128x128 tile, BK=64, 4 waves (2x2), global_load_lds w16, XOR-swizzled src.
// Epilogue: P = amask*exp(S*scale) -> bf16 (LDS-staged, coalesced store);
// per-row partials -> l_part[b][nt][r].  Blocks beyond Mpad exit.
// ---------------------------------------------------------------------------
__global__ __launch_bounds__(256, 2)
void attn_gemm1(const unsigned short* __restrict__ Qp,
                const unsigned short* __restrict__ Kp,
                const int* __restrict__ amask, const int* __restrict__ meta,
                float* __restrict__ lpart_out,
                unsigned short* __restrict__ P_out)
{
  const int m0 = blockIdx.x * 128;
  if (m0 >= meta[0]) return;
  const int n0 = blockIdx.y * 128;
  const int b  = blockIdx.z;
  const int tid = threadIdx.x;
  const int lane = tid & 63, wv = tid >> 6;
  const int lrow = lane & 15, khi = lane >> 4;
  const int wr = wv >> 1, wc = wv & 1;

  __shared__ __align__(16) unsigned short smem[128 * 128]; // a|b tiles, then P
  unsigned short* a_lds = smem;              // 128*64
  unsigned short* b_lds = smem + 128 * 64;   // 128*64
  __shared__ float red_lds[128 * 2];

  const unsigned short* Kb = Kp + (size_t)b * NN * II;

  f32x4 acc[4][4] = {};

  for (int kc = 0; kc < 12; ++kc) {
    const int k0 = kc * 64;
    __syncthreads();
    #pragma unroll
    for (int u = 0; u < 4; ++u) {
      int idx = u * 256 + tid;          // 1024 slots of 8 bf16 (16B)
      int row = idx >> 3, g = idx & 7;
      int sg = g ^ (row & 7);
      GLOAD_LDS16(Qp + (size_t)(m0 + row) * II + k0 + sg * 8, &a_lds[idx * 8]);
      GLOAD_LDS16(Kb + (size_t)(n0 + row) * II + k0 + sg * 8, &b_lds[idx * 8]);
    }
    __syncthreads();
    #pragma unroll
    for (int s = 0; s < 2; ++s) {
      short8 af[4], bf[4];
      #pragma unroll
      for (int m = 0; m < 4; ++m) {
        int ar = wr * 64 + m * 16 + lrow;
        int g = s * 4 + khi;
        af[m] = *(const short8*)&a_lds[(ar * 8 + (g ^ (ar & 7))) * 8];
      }
      #pragma unroll
      for (int f = 0; f < 4; ++f) {
        int br = wc * 64 + f * 16 + lrow;
        int g = s * 4 + khi;
        bf[f] = *(const short8*)&b_lds[(br * 8 + (g ^ (br & 7))) * 8];
      }
      #pragma unroll
      for (int m = 0; m < 4; ++m)
        #pragma unroll
        for (int f = 0; f < 4; ++f)
          acc[m][f] = __builtin_amdgcn_mfma_f32_16x16x32_bf16(af[m], bf[f], acc[m][f], 0, 0, 0);
    }
  }

  float msk[4];
  #pragma unroll
  for (int f = 0; f < 4; ++f)
    msk[f] = (amask[b * NN + n0 + wc * 64 + f * 16 + lrow] != 0) ? 1.0f : 0.0f;

  __syncthreads();   // done with a_lds/b_lds; repurpose smem as P tile

  #pragma unroll
  for (int m = 0; m < 4; ++m) {
    #pragma unroll
    for (int r = 0; r < 4; ++r) {
      const int row = wr * 64 + m * 16 + khi * 4 + r;     // 0..127 local
      const int s8 = (row & 7) << 3;
      float rs = 0.0f;
      #pragma unroll
      for (int f = 0; f < 4; ++f) {
        float pe = msk[f] * __expf(acc[m][f][r] * SCALE);
        rs += pe;
        int col = wc * 64 + f * 16 + lrow;
        smem[row * 128 + (col ^ s8)] = f2bf(pe);
      }
      rs += __shfl_xor(rs, 1); rs += __shfl_xor(rs, 2);
      rs += __shfl_xor(rs, 4); rs += __shfl_xor(rs, 8);
      if (lrow == 0) red_lds[row * 2 + wc] = rs;
    }
  }
  __syncthreads();
  if (tid < 128)
    lpart_out[((size_t)(b * 16 + blockIdx.y) << 14) + m0 + tid] =
        red_lds[tid * 2] + red_lds[tid * 2 + 1];
  unsigned short* Pb = P_out + (size_t)b * MM * NN;
  #pragma unroll
  for (int u = 0; u < 8; ++u) {
    int idx = u * 256 + tid;            // 2048 uint4 slots
    int row = idx >> 4, q = idx & 15;
    int gcol = (q ^ (row & 7)) << 3;
    *(uint4*)(Pb + (size_t)(m0 + row) * NN + n0 + gcol) =
        *(const uint4*)&smem[row * 128 + q * 8];
  }
}

// ---------------------------------------------------------------------------
// pp[b,c,n] = (1/cnt_c) * sum_{r in [cs_c, cs_c+cnt_c)} P[b][r][n] / l_r
// One block per (c,b); 256 threads x 8 bf16 = full n-row.
// ---------------------------------------------------------------------------
__global__ __launch_bounds__(256)
void ppred_kernel(const unsigned short* __restrict__ P,
                  const float* __restrict__ lpart,
                  const int* __restrict__ cstart, const int* __restrict__ ccnt,
                  unsigned short* __restrict__ pp)
{
  const int c = blockIdx.x, b = blockIdx.y;
  const int tid = threadIdx.x;
  const int cs = cstart[c], cnt = ccnt[c];
  __shared__ float wgt[64];
  if (tid < cnt) {
    float lv = 0.0f;
    #pragma unroll
    for (int nt = 0; nt < 16; ++nt)
      lv += lpart[(((size_t)(b * 16 + nt)) << 14) + cs + tid];
    wgt[tid] = 1.0f / lv;
  }
  __syncthreads();
  const float invd = 1.0f / (float)cnt;
  float acc[8] = {};
  const unsigned short* Pr = P + ((size_t)b * MM + cs) * NN + tid * 8;
  #pragma unroll 4
  for (int d = 0; d < cnt; ++d) {
    U8 v; v.v = *(const uint4*)(Pr + (size_t)d * NN);
    float w = wgt[d];
    #pragma unroll
    for (int e = 0; e < 8; ++e) acc[e] += w * bf2f(v.us[e]);
  }
  U8 o;
  #pragma unroll
  for (int e = 0; e < 8; ++e) o.us[e] = f2bf(acc[e] * invd);
  *(uint4*)(pp + ((size_t)(b * CC + c)) * NN + tid * 8) = o.v;
}

// ---------------------------------------------------------------------------
// PV GEMM: pooled[mc][j] = sum_n pp[mc][n] * Vt[b*II + j][n]   (f32 out)
// 64x64 tile, 4 waves, K-chunks of 128 over n=2048.
// ---------------------------------------------------------------------------
__global__ __launch_bounds__(256, 2)
void pv_gemm(const unsigned short* __restrict__ pp,
             const unsigned short* __restrict__ Vt,
             float* __restrict__ pooled)
{
  const int m0 = blockIdx.x * 64;
  const int j0 = blockIdx.y * 64;
  const int b  = m0 >> 8;
  const int tid = threadIdx.x;
  const int lane = tid & 63, wv = tid >> 6;
  const int lrow = lane & 15, khi = lane >> 4;

  __shared__ __align__(16) unsigned short a_lds[64 * 128];
  __shared__ __align__(16) unsigned short b_lds[64 * 128];

  f32x4 acc[4] = {};

  for (int kc = 0; kc < 16; ++kc) {
    const int k0 = kc * 128;
    __syncthreads();
    #pragma unroll
    for (int u = 0; u < 4; ++u) {
      int idx = u * 256 + tid;          // 1024 slots of 8 bf16
      int row = idx >> 4, g = idx & 15;
      int sg = g ^ (row & 7);
      GLOAD_LDS16(pp + (size_t)(m0 + row) * NN + k0 + sg * 8, &a_lds[idx * 8]);
      GLOAD_LDS16(Vt + ((size_t)b * II + j0 + row) * NN + k0 + sg * 8, &b_lds[idx * 8]);
    }
    __syncthreads();
    #pragma unroll
    for (int s = 0; s < 4; ++s) {
      int g = s * 4 + khi;
      int ar = 16 * wv + lrow;
      short8 af = *(const short8*)&a_lds[(ar * 16 + (g ^ (ar & 7))) * 8];
      #pragma unroll
      for (int f = 0; f < 4; ++f) {
        int br = f * 16 + lrow;
        short8 bfr = *(const short8*)&b_lds[(br * 16 + (g ^ (br & 7))) * 8];
        acc[f] = __builtin_amdgcn_mfma_f32_16x16x32_bf16(af, bfr, acc[f], 0, 0, 0);
      }
    }
  }
  #pragma unroll
  for (int f = 0; f < 4; ++f)
    #pragma unroll
    for (int r = 0; r < 4; ++r) {
      int row = m0 + 16 * wv + khi * 4 + r;
      int col = j0 + f * 16 + lrow;
      pooled[(size_t)row * II + col] = acc[f][r];
    }
}

// ---------------------------------------------------------------------------
// LayerNorm over i + dot with Wo.  One block per (b,c).
// ---------------------------------------------------------------------------
__global__ __launch_bounds__(256)
void ln_out_kernel(const float* __restrict__ pooled, const float* __restrict__ g,
                   const float* __restrict__ beta, const float* __restrict__ Wo,
                   const float* __restrict__ bo, float* __restrict__ out)
{
  const int bc = blockIdx.x;
  const int tid = threadIdx.x;
  const int lane = tid & 63, wv = tid >> 6;
  const float* row = pooled + (size_t)bc * II;
  float x0 = row[tid], x1 = row[tid + 256], x2 = row[tid + 512];
  float s = x0 + x1 + x2;
  float sq = x0 * x0 + x1 * x1 + x2 * x2;
  #pragma unroll
  for (int m = 1; m < 64; m <<= 1) { s += __shfl_xor(s, m); sq += __shfl_xor(sq, m); }
  __shared__ float red[8];
  if (lane == 0) { red[wv] = s; red[4 + wv] = sq; }
  __syncthreads();
  s = red[0] + red[1] + red[2] + red[3];
  sq = red[4] + red[5] + red[6] + red[7];
  const float mu = s * (1.0f / 768.0f);
  const float var = sq * (1.0f / 768.0f) - mu * mu;
  const float rs = rsqrtf(var + 1e-5f);
  float dot = ((x0 - mu) * rs * g[tid] + beta[tid]) * Wo[tid]
            + ((x1 - mu) * rs * g[tid + 256] + beta[tid + 256]) * Wo[tid + 256]
            + ((x2 - mu) * rs * g[tid + 512] + beta[tid + 512]) * Wo[tid + 512];
  #pragma unroll
  for (int m = 1; m < 64; m <<= 1) dot += __shfl_xor(dot, m);
  __syncthreads();
  if (lane == 0) red[wv] = dot;
  __syncthreads();
  if (tid == 0) out[bc] = red[0] + red[1] + red[2] + red[3] + bo[0];
}

// ---------------------------------------------------------------------------
extern "C" void kernel_launch(void* const* d_in, const int* in_sizes, int n_in,
                              void* d_out, int out_size, void* d_ws, size_t ws_size,
                              hipStream_t stream) {
  const float* x     = (const float*)d_in[0];   // [B,N,I]
  const int*   amask = (const int*)d_in[1];     // [B,N]
  const float* demb  = (const float*)d_in[2];   // [C,D,I]
  const int*   dmask = (const int*)d_in[3];     // [C,D]
  const float* Wq    = (const float*)d_in[4];
  const float* Wk    = (const float*)d_in[5];
  const float* Wv    = (const float*)d_in[6];
  const float* Wo    = (const float*)d_in[7];   // [1,I]
  const float* bo    = (const float*)d_in[8];   // [1]
  const float* lng   = (const float*)d_in[9];
  const float* lnb   = (const float*)d_in[10];

  char* ws = (char*)d_ws;
  // Region A (0 .. 134.2MB): conversion buffers, later overwritten by P.
  const size_t OFF_QB  = 0;                                   // 25.2 MB
  const size_t OFF_XB  = OFF_QB + (size_t)MM * II * 2;        // 6.3 MB
  const size_t OFF_WQB = OFF_XB + (size_t)BB * NN * II * 2;   // 1.2 MB
  const size_t OFF_WKB = OFF_WQB + (size_t)II * II * 2;
  const size_t OFF_WVB = OFF_WKB + (size_t)II * II * 2;
  const size_t OFF_P   = 0;                                   // 134.2 MB
  // Region B (after P):
  const size_t OFF_QP = (size_t)BB * MM * NN * 2;             // 25.2 MB
  const size_t OFF_KP = OFF_QP + (size_t)MM * II * 2;         // 6.3 MB
  const size_t OFF_VT = OFF_KP + (size_t)BB * NN * II * 2;    // 6.3 MB
  const size_t OFF_LP = OFF_VT + (size_t)BB * II * NN * 2;    // 4.2 MB
  const size_t OFF_PP = OFF_LP + (size_t)BB * 16 * MM * 4;    // 2.1 MB
  const size_t OFF_PL = OFF_PP + (size_t)BB * CC * NN * 2;    // 1.6 MB
  const size_t OFF_IDX = OFF_PL + (size_t)BB * CC * II * 4;   // 64 KB
  const size_t OFF_CS  = OFF_IDX + (size_t)MM * 4;            // 1 KB
  const size_t OFF_CNT = OFF_CS + (size_t)CC * 4;             // 1 KB
  const size_t OFF_MET = OFF_CNT + (size_t)CC * 4;            // 4 B

  unsigned short* Qb  = (unsigned short*)(ws + OFF_QB);
  unsigned short* xb  = (unsigned short*)(ws + OFF_XB);
  unsigned short* Wqb = (unsigned short*)(ws + OFF_WQB);
  unsigned short* Wkb = (unsigned short*)(ws + OFF_WKB);
  unsigned short* Wvb = (unsigned short*)(ws + OFF_WVB);
  unsigned short* P   = (unsigned short*)(ws + OFF_P);
  unsigned short* Qp  = (unsigned short*)(ws + OFF_QP);
  unsigned short* Kp  = (unsigned short*)(ws + OFF_KP);
  unsigned short* Vt  = (unsigned short*)(ws + OFF_VT);
  float* l_part = (float*)(ws + OFF_LP);
  unsigned short* pp = (unsigned short*)(ws + OFF_PP);
  float* pooled = (float*)(ws + OFF_PL);
  int* idx    = (int*)(ws + OFF_IDX);
  int* cstart = (int*)(ws + OFF_CS);
  int* ccnt   = (int*)(ws + OFF_CNT);
  int* meta   = (int*)(ws + OFF_MET);

  scan_kernel<<<1, 256, 0, stream>>>(dmask, idx, cstart, ccnt, meta);
  cvt_kernel<<<2048, 256, 0, stream>>>(demb, x, Wq, Wk, Wv, dmask,
                                       Qb, xb, Wqb, Wkb, Wvb);

  proj128<0, 1><<<dim3(MM / 128, II / 128), 256, 0, stream>>>(Qb, Wqb, Qp, idx, meta);
  proj128<0, 0><<<dim3((BB * NN) / 128, II / 128), 256, 0, stream>>>(xb, Wkb, Kp, nullptr, nullptr);
  proj128<1, 0><<<dim3((BB * NN) / 128, II / 128), 256, 0, stream>>>(xb, Wvb, Vt, nullptr, nullptr);

  attn_gemm1<<<dim3(MM / 128, NN / 128, BB), 256, 0, stream>>>(
      Qp, Kp, amask, meta, l_part, P);
  ppred_kernel<<<dim3(CC, BB), 256, 0, stream>>>(P, l_part, cstart, ccnt, pp);

  pv_gemm<<<dim3((BB * CC) / 64, II / 64), 256, 0, stream>>>(pp, Vt, pooled);
  ln_out_kernel<<<BB * CC, 256, 0, stream>>>(pooled, lng, lnb, Wo, bo, (float*)d_out);
}